// Round 7
// baseline (290.716 us; speedup 1.0000x reference)
//
#include <hip/hip_runtime.h>
#include <hip/hip_bf16.h>

#define N_NODES   40000
#define N_EDGES   640000
#define IN_CH     128
#define HID1      512
#define HID2      256
#define OUT_CH    2
#define NUM_GRAPHS 16
#define EPSF      1e-5f
#define SCAN_NB   157                 // ceil(40000/256)
#define FIXSC     1048576.0f          // 2^20 fixed-point scale for edge weights

typedef unsigned short u16;
typedef unsigned int   u32;
typedef unsigned long long u64;
using short8 = __attribute__((ext_vector_type(8))) short;
using f32x4  = __attribute__((ext_vector_type(4))) float;

__device__ __forceinline__ float b2f(u16 u) {
    return __uint_as_float(((u32)u) << 16);
}
__device__ __forceinline__ u16 f2b(float f) {
    u32 u = __float_as_uint(f);
    u32 r = (u + 0x7FFFu + ((u >> 16) & 1u)) >> 16;   // RNE
    return (u16)r;
}
__device__ __forceinline__ void gload_lds16(const u16* g, u16* l) {
    __builtin_amdgcn_global_load_lds((const __attribute__((address_space(1))) u32*)g,
                                     (__attribute__((address_space(3))) u32*)l, 16, 0, 0);
}

// ------- pass 1: one u64 atomic per edge: cnt(high24) | fix20(ew) (low40) ---
__global__ __launch_bounds__(256) void pack_kernel(const int* __restrict__ dst,
                                                   const float* __restrict__ ew,
                                                   u64* __restrict__ packed,
                                                   int* __restrict__ eoff) {
    int t = blockIdx.x * blockDim.x + threadIdx.x;
    if (t >= N_EDGES) return;
    int d = dst[t];
    u64 inc = (1ull << 40) | (u64)__float2uint_rn(ew[t] * FIXSC);
    u64 old = atomicAdd(&packed[d], inc);
    eoff[t] = (int)(old >> 40);
}

// ---- scan phase 1 (fused unpack): packed -> dinv, local-excl rowptr, blocksum
__global__ __launch_bounds__(256) void scan_p1_kernel(const u64* __restrict__ packed,
                                                      float* __restrict__ dinv,
                                                      int* __restrict__ rowptr,
                                                      int* __restrict__ blocksum) {
    __shared__ int sd[256];
    const int t = threadIdx.x;
    const int i = blockIdx.x * 256 + t;
    int v = 0;
    if (i < N_NODES) {
        u64 p = packed[i];
        v = (int)(p >> 40);
        float deg = (float)(p & ((1ull << 40) - 1)) * (1.0f / FIXSC);
        dinv[i] = rsqrtf(deg + 1.0f);              // +1 self-loop
    }
    sd[t] = v;
    __syncthreads();
    for (int off = 1; off < 256; off <<= 1) {
        int u = (t >= off) ? sd[t - off] : 0;
        __syncthreads();
        sd[t] += u;
        __syncthreads();
    }
    if (i < N_NODES) rowptr[i] = sd[t] - v;        // local exclusive
    if (t == 255) blocksum[blockIdx.x] = sd[255];
}

__global__ __launch_bounds__(256) void scan_p2_kernel(int* __restrict__ blocksum,
                                                      int* __restrict__ bprefix) {
    __shared__ int sd[256];
    const int t = threadIdx.x;
    const int v = (t < SCAN_NB) ? blocksum[t] : 0;
    sd[t] = v;
    __syncthreads();
    for (int off = 1; off < 256; off <<= 1) {
        int u = (t >= off) ? sd[t - off] : 0;
        __syncthreads();
        sd[t] += u;
        __syncthreads();
    }
    bprefix[t] = sd[t] - v;                        // exclusive block prefix
}

__global__ __launch_bounds__(256) void scan_p3_kernel(int* __restrict__ rowptr,
                                                      const int* __restrict__ bprefix) {
    const int i = blockIdx.x * 256 + threadIdx.x;
    if (i < N_NODES) rowptr[i] += bprefix[blockIdx.x];
    if (i == 0) rowptr[N_NODES] = N_EDGES;
}

// -------- scatter edges into CSR (atomic-free); pair = (src, norm-bits) ----
__global__ __launch_bounds__(256) void scatter_kernel(const int* __restrict__ src,
                                                      const int* __restrict__ dst,
                                                      const float* __restrict__ ew,
                                                      const float* __restrict__ dinv,
                                                      const int* __restrict__ rowptr,
                                                      const int* __restrict__ eoff,
                                                      int2* __restrict__ csr_pair) {
    int t = blockIdx.x * blockDim.x + threadIdx.x;
    if (t >= N_EDGES) return;
    int s = src[t], d = dst[t];
    int pos = rowptr[d] + eoff[t];
    float norm = dinv[s] * ew[t] * dinv[d];
    int2 pr; pr.x = s; pr.y = __float_as_int(norm);
    csr_pair[pos] = pr;
}

// ---------------- casts / transposes ----------------
__global__ __launch_bounds__(256) void cast_x_kernel(const float* __restrict__ x,
                                                     u16* __restrict__ xb) {
    int t = blockIdx.x * blockDim.x + threadIdx.x;
    if (t < N_NODES * IN_CH / 4) {
        float4 v = ((const float4*)x)[t];
        ushort4 o = { f2b(v.x), f2b(v.y), f2b(v.z), f2b(v.w) };
        ((ushort4*)xb)[t] = o;
    }
}

// W[R][C] f32 -> WT[C][R] bf16
__global__ __launch_bounds__(256) void transpose_cast_kernel(const float* __restrict__ W,
                                                             u16* __restrict__ WT,
                                                             int R, int Ccols) {
    int idx = blockIdx.x * blockDim.x + threadIdx.x;
    if (idx >= R * Ccols) return;
    int r = idx / Ccols, c = idx % Ccols;
    WT[(size_t)c * R + r] = f2b(W[idx]);
}

// ---------------- CSR aggregation, bf16 -> bf16 (C=128), 16x unrolled ------
__global__ __launch_bounds__(256) void agg128_kernel(const int* __restrict__ rowptr,
                                                     const int2* __restrict__ csr_pair,
                                                     const float* __restrict__ dinv,
                                                     const u16* __restrict__ xb,
                                                     u16* __restrict__ outb) {
    const int node = (blockIdx.x * blockDim.x + threadIdx.x) >> 6;
    const int lane = threadIdx.x & 63;
    if (node >= N_NODES) return;
    const float ds = dinv[node];
    const float wself = ds * ds;
    const int e0 = rowptr[node], e1 = rowptr[node + 1];
    const int c0 = lane * 2;

    ushort2 v = *(const ushort2*)&xb[(size_t)node * IN_CH + c0];
    float ax = wself * b2f(v.x), ay = wself * b2f(v.y);
    int e = e0;
    for (; e + 16 <= e1; e += 16) {
        int2 pi[16]; ushort2 ui[16];
#pragma unroll
        for (int j = 0; j < 16; ++j) pi[j] = csr_pair[e + j];
#pragma unroll
        for (int j = 0; j < 16; ++j) ui[j] = *(const ushort2*)&xb[(size_t)pi[j].x * IN_CH + c0];
#pragma unroll
        for (int j = 0; j < 16; ++j) {
            float w = __int_as_float(pi[j].y);
            ax += w * b2f(ui[j].x);
            ay += w * b2f(ui[j].y);
        }
    }
    for (; e < e1; ++e) {
        int2 p = csr_pair[e];
        float w = __int_as_float(p.y);
        ushort2 u = *(const ushort2*)&xb[(size_t)p.x * IN_CH + c0];
        ax += w * b2f(u.x);
        ay += w * b2f(u.y);
    }
    ushort2 o = { f2b(ax), f2b(ay) };
    *(ushort2*)&outb[(size_t)node * IN_CH + c0] = o;
}

// ------- CSR aggregation + bias + ReLU + LayerNorm (C=256), 16x unrolled ---
__global__ __launch_bounds__(256) void agg256_ln_kernel(const int* __restrict__ rowptr,
                                                        const int2* __restrict__ csr_pair,
                                                        const float* __restrict__ dinv,
                                                        const u16* __restrict__ hwb,
                                                        const float* __restrict__ bias,
                                                        const float* __restrict__ g,
                                                        const float* __restrict__ be,
                                                        float* __restrict__ out) {
    const int node = (blockIdx.x * blockDim.x + threadIdx.x) >> 6;
    const int lane = threadIdx.x & 63;
    if (node >= N_NODES) return;
    const float ds = dinv[node];
    const float wself = ds * ds;
    const int e0 = rowptr[node], e1 = rowptr[node + 1];
    const int c0 = lane * 4;

    ushort4 v = *(const ushort4*)&hwb[(size_t)node * HID2 + c0];
    float4 acc = { wself * b2f(v.x), wself * b2f(v.y), wself * b2f(v.z), wself * b2f(v.w) };
    int e = e0;
    for (; e + 16 <= e1; e += 16) {
        int2 pi[16]; ushort4 ui[16];
#pragma unroll
        for (int j = 0; j < 16; ++j) pi[j] = csr_pair[e + j];
#pragma unroll
        for (int j = 0; j < 16; ++j) ui[j] = *(const ushort4*)&hwb[(size_t)pi[j].x * HID2 + c0];
#pragma unroll
        for (int j = 0; j < 16; ++j) {
            float w = __int_as_float(pi[j].y);
            acc.x += w * b2f(ui[j].x);
            acc.y += w * b2f(ui[j].y);
            acc.z += w * b2f(ui[j].z);
            acc.w += w * b2f(ui[j].w);
        }
    }
    for (; e < e1; ++e) {
        int2 p = csr_pair[e];
        float w = __int_as_float(p.y);
        ushort4 u = *(const ushort4*)&hwb[(size_t)p.x * HID2 + c0];
        acc.x += w * b2f(u.x);
        acc.y += w * b2f(u.y);
        acc.z += w * b2f(u.z);
        acc.w += w * b2f(u.w);
    }
    // fused bias + ReLU + LayerNorm
    float vv[4];
    float sum = 0.f, sq = 0.f;
#pragma unroll
    for (int j = 0; j < 4; ++j) {
        float xv = ((const float*)&acc)[j] + bias[c0 + j];
        xv = fmaxf(xv, 0.f);
        vv[j] = xv;
        sum += xv;
        sq += xv * xv;
    }
#pragma unroll
    for (int off = 32; off >= 1; off >>= 1) {
        sum += __shfl_xor(sum, off);
        sq  += __shfl_xor(sq, off);
    }
    const float mean = sum * (1.0f / HID2);
    const float var = sq * (1.0f / HID2) - mean * mean;
    const float r = rsqrtf(var + EPSF);
    float4 o;
    o.x = (vv[0] - mean) * r * g[c0 + 0] + be[c0 + 0];
    o.y = (vv[1] - mean) * r * g[c0 + 1] + be[c0 + 1];
    o.z = (vv[2] - mean) * r * g[c0 + 2] + be[c0 + 2];
    o.w = (vv[3] - mean) * r * g[c0 + 3] + be[c0 + 3];
    *(float4*)&out[(size_t)node * HID2 + c0] = o;
}

// ---------------- MFMA GEMM, 128x128 tile, 4 waves, global_load_lds --------
template <int K, int N, int ASTRIDE>
__global__ __launch_bounds__(256) void mfma_gemm128(const u16* __restrict__ A,
                                                    const u16* __restrict__ BT,
                                                    u16* __restrict__ Cb) {
    __shared__ u16 As[128 * 32];
    __shared__ u16 Bs[128 * 32];
    const int t = threadIdx.x;
    const int rowbase = blockIdx.x * 128;
    const int colbase = blockIdx.y * 128;
    const int l = t & 63;
    const int wv = t >> 6;
    const int wm = (wv >> 1) * 64;
    const int wn = (wv & 1) * 64;
    const int fr = l & 15;
    const int fg = l >> 4;

    f32x4 acc[4][4];
#pragma unroll
    for (int a = 0; a < 4; ++a)
#pragma unroll
        for (int b = 0; b < 4; ++b)
            acc[a][b] = (f32x4){0.f, 0.f, 0.f, 0.f};

    const int c0i = wv * 128 + l;
    const int c1i = c0i + 64;
    int ar0 = rowbase + (c0i >> 2); if (ar0 >= N_NODES) ar0 = N_NODES - 1;
    int ar1 = rowbase + (c1i >> 2); if (ar1 >= N_NODES) ar1 = N_NODES - 1;
    const u16* ag0 = A + (size_t)ar0 * ASTRIDE + (c0i & 3) * 8;
    const u16* ag1 = A + (size_t)ar1 * ASTRIDE + (c1i & 3) * 8;
    const u16* bg0 = BT + (size_t)(colbase + (c0i >> 2)) * K + (c0i & 3) * 8;
    const u16* bg1 = BT + (size_t)(colbase + (c1i >> 2)) * K + (c1i & 3) * 8;
    u16* al0 = As + c0i * 8;
    u16* al1 = As + c1i * 8;
    u16* bl0 = Bs + c0i * 8;
    u16* bl1 = Bs + c1i * 8;

    for (int k0 = 0; k0 < K; k0 += 32) {
        gload_lds16(ag0 + k0, al0);
        gload_lds16(ag1 + k0, al1);
        gload_lds16(bg0 + k0, bl0);
        gload_lds16(bg1 + k0, bl1);
        __syncthreads();

        short8 af[4], bf[4];
#pragma unroll
        for (int fm = 0; fm < 4; ++fm)
            af[fm] = *(const short8*)&As[(wm + fm * 16 + fr) * 32 + fg * 8];
#pragma unroll
        for (int fn = 0; fn < 4; ++fn)
            bf[fn] = *(const short8*)&Bs[(wn + fn * 16 + fr) * 32 + fg * 8];
#pragma unroll
        for (int fm = 0; fm < 4; ++fm)
#pragma unroll
            for (int fn = 0; fn < 4; ++fn)
                acc[fm][fn] = __builtin_amdgcn_mfma_f32_16x16x32_bf16(af[fm], bf[fn], acc[fm][fn], 0, 0, 0);
        __syncthreads();
    }

#pragma unroll
    for (int fm = 0; fm < 4; ++fm)
#pragma unroll
        for (int fn = 0; fn < 4; ++fn) {
#pragma unroll
            for (int i = 0; i < 4; ++i) {
                int row = rowbase + wm + fm * 16 + fg * 4 + i;
                if (row < N_NODES) {
                    int col = colbase + wn + fn * 16 + fr;
                    Cb[(size_t)row * N + col] = f2b(acc[fm][fn][i]);
                }
            }
        }
}

// ------- bias + ReLU + LayerNorm, C=512, bf16 in/out, dense, vectorized ----
__global__ __launch_bounds__(256) void relu_ln512b_kernel(u16* __restrict__ io,
                                                          const float* __restrict__ bias,
                                                          const float* __restrict__ g,
                                                          const float* __restrict__ be) {
    const int wv = (blockIdx.x * blockDim.x + threadIdx.x) >> 6;
    const int lane = threadIdx.x & 63;
    if (wv >= N_NODES) return;
    u16* __restrict__ row = io + (size_t)wv * HID1;
    const int c0 = lane * 8;
    short8 raw = *(const short8*)&row[c0];
    float v[8];
    float sum = 0.f, sq = 0.f;
#pragma unroll
    for (int j = 0; j < 8; ++j) {
        float xv = b2f((u16)raw[j]) + bias[c0 + j];
        xv = fmaxf(xv, 0.f);
        v[j] = xv;
        sum += xv;
        sq += xv * xv;
    }
#pragma unroll
    for (int off = 32; off >= 1; off >>= 1) {
        sum += __shfl_xor(sum, off);
        sq  += __shfl_xor(sq, off);
    }
    const float mean = sum * (1.0f / HID1);
    const float var = sq * (1.0f / HID1) - mean * mean;
    const float r = rsqrtf(var + EPSF);
    short8 o;
#pragma unroll
    for (int j = 0; j < 8; ++j)
        o[j] = (short)f2b((v[j] - mean) * r * g[c0 + j] + be[c0 + j]);
    *(short8*)&row[c0] = o;
}

// ---------------- graph boundaries (batch is sorted) ----------------
__global__ __launch_bounds__(64) void bounds_kernel(const int* __restrict__ batch,
                                                    int* __restrict__ gstart) {
    int g = threadIdx.x;
    if (g > NUM_GRAPHS) return;
    int lo = 0, hi = N_NODES;
    while (lo < hi) {
        int mid = (lo + hi) >> 1;
        if (batch[mid] < g) lo = mid + 1; else hi = mid;
    }
    gstart[g] = lo;
}

// ---------------- pool stage: per (graph, chunk) partial sums --------------
__global__ __launch_bounds__(256) void pool2_kernel(const float* __restrict__ h3,
                                                    const int* __restrict__ gstart,
                                                    float* __restrict__ pooled) {
    const int g = blockIdx.x, chunk = blockIdx.y;
    const int s = gstart[g], e = gstart[g + 1];
    const int len = e - s;
    const int c0 = s + (len * chunk) / 16;
    const int c1 = s + (len * (chunk + 1)) / 16;
    float acc = 0.f;
    for (int n = c0; n < c1; ++n)
        acc += h3[(size_t)n * HID2 + threadIdx.x];
    atomicAdd(&pooled[g * HID2 + threadIdx.x], acc);
}

// ---------------- final FC ----------------
__global__ __launch_bounds__(64) void fc_kernel(const float* __restrict__ pooled,
                                                const int* __restrict__ gstart,
                                                const float* __restrict__ Wfc,
                                                const float* __restrict__ bfc,
                                                float* __restrict__ out) {
    const int t = threadIdx.x;
    if (t >= NUM_GRAPHS * OUT_CH) return;
    const int g = t >> 1;
    const int o = t & 1;
    const int len = gstart[g + 1] - gstart[g];
    const float inv = 1.0f / fmaxf((float)len, 1.0f);
    float s = 0.f;
    for (int k = 0; k < HID2; ++k)
        s += pooled[g * HID2 + k] * Wfc[k * OUT_CH + o];
    out[t] = s * inv + bfc[o];
}

extern "C" void kernel_launch(void* const* d_in, const int* in_sizes, int n_in,
                              void* d_out, int out_size, void* d_ws, size_t ws_size,
                              hipStream_t stream) {
    const float* x   = (const float*)d_in[0];
    const int*   ei  = (const int*)d_in[1];
    const float* ew  = (const float*)d_in[2];
    const int*   bat = (const int*)d_in[3];
    const float* W1  = (const float*)d_in[4];
    const float* b1  = (const float*)d_in[5];
    const float* g1  = (const float*)d_in[6];
    const float* be1 = (const float*)d_in[7];
    const float* W2  = (const float*)d_in[8];
    const float* b2  = (const float*)d_in[9];
    const float* g2  = (const float*)d_in[10];
    const float* be2 = (const float*)d_in[11];
    const float* Wfc = (const float*)d_in[12];
    const float* bfc = (const float*)d_in[13];

    const int* srcArr = ei;
    const int* dstArr = ei + N_EDGES;

    float* out = (float*)d_out;
    float* h3  = out;                                   // [40000, 256] f32
    float* fcO = out + (size_t)N_NODES * HID2;

    // workspace layout (f32-element offsets; packed is 8B-aligned at base)
    float* ws       = (float*)d_ws;
    u64*   packed   = (u64*)ws;                         // 40960 u64  (81920 f32)
    float* dinv     = ws + 81920;                       // 40960
    int*   rowptr   = (int*)(ws + 122880);              // 41088 (41001 used)
    int*   gstart   = (int*)(ws + 163968);              // 64
    int*   blocksum = (int*)(ws + 164032);              // 256
    int*   bprefix  = (int*)(ws + 164288);              // 256
    int*   eoff     = (int*)(ws + 164544);              // 640000
    int2*  csr_pair = (int2*)(ws + 804544);             // 640000 int2 (1280000 f32)
    u16*   xb       = (u16*)(ws + 2084544);             // 40000*128 u16
    u16*   agg1b    = (u16*)(ws + 4644544);             // 40000*128 u16
    u16*   hb       = (u16*)(ws + 7204544);             // 40000*512 u16 (dense bf16 h)
    u16*   hwb      = (u16*)(ws + 17444544);            // 40000*256 u16
    u16*   W1T      = (u16*)(ws + 22564544);            // 512*128 u16
    u16*   W2T      = (u16*)(ws + 22597312);            // 256*512 u16
    float* pooled   = ws + 22662848;                    // 16*256

    // 1. degree/count/slot in ONE atomic pass + CSR build (atomic-free scatter)
    hipMemsetAsync(packed, 0, 40960 * sizeof(u64), stream);
    pack_kernel<<<(N_EDGES + 255) / 256, 256, 0, stream>>>(dstArr, ew, packed, eoff);
    scan_p1_kernel<<<SCAN_NB, 256, 0, stream>>>(packed, dinv, rowptr, blocksum);
    scan_p2_kernel<<<1, 256, 0, stream>>>(blocksum, bprefix);
    scan_p3_kernel<<<SCAN_NB, 256, 0, stream>>>(rowptr, bprefix);
    scatter_kernel<<<(N_EDGES + 255) / 256, 256, 0, stream>>>(
        srcArr, dstArr, ew, dinv, rowptr, eoff, csr_pair);

    // 2. param prep
    cast_x_kernel<<<(N_NODES * IN_CH / 4 + 255) / 256, 256, 0, stream>>>(x, xb);
    transpose_cast_kernel<<<(IN_CH * HID1 + 255) / 256, 256, 0, stream>>>(W1, W1T, IN_CH, HID1);
    transpose_cast_kernel<<<(HID1 * HID2 + 255) / 256, 256, 0, stream>>>(W2, W2T, HID1, HID2);

    // 3. layer 1: agg1 = A_norm @ x (bf16), h = agg1 @ W1 (MFMA -> bf16), relu+LN bf16
    agg128_kernel<<<(N_NODES + 3) / 4, 256, 0, stream>>>(
        rowptr, csr_pair, dinv, xb, agg1b);
    {
        dim3 grid((N_NODES + 127) / 128, HID1 / 128);
        mfma_gemm128<IN_CH, HID1, IN_CH><<<grid, 256, 0, stream>>>(agg1b, W1T, hb);
    }
    relu_ln512b_kernel<<<(N_NODES + 3) / 4, 256, 0, stream>>>(hb, b1, g1, be1);

    // 4. layer 2: hw = h @ W2 (MFMA -> bf16), h3 = A_norm @ hw fused relu+LN
    {
        dim3 grid((N_NODES + 127) / 128, HID2 / 128);
        mfma_gemm128<HID1, HID2, HID1><<<grid, 256, 0, stream>>>(hb, W2T, hwb);
    }
    agg256_ln_kernel<<<(N_NODES + 3) / 4, 256, 0, stream>>>(
        rowptr, csr_pair, dinv, hwb, b2, g2, be2, h3);

    // 5. pool + fc
    bounds_kernel<<<1, 64, 0, stream>>>(bat, gstart);
    hipMemsetAsync(pooled, 0, NUM_GRAPHS * HID2 * sizeof(float), stream);
    {
        dim3 grid(NUM_GRAPHS, 16);
        pool2_kernel<<<grid, 256, 0, stream>>>(h3, gstart, pooled);
    }
    fc_kernel<<<1, 64, 0, stream>>>(pooled, gstart, Wfc, bfc, fcO);
}

// Round 8
// 264.077 us; speedup vs baseline: 1.1009x; 1.1009x over previous
//
#include <hip/hip_runtime.h>
#include <hip/hip_bf16.h>

#define N_NODES   40000
#define N_EDGES   640000
#define IN_CH     128
#define HID1      512
#define HID2      256
#define OUT_CH    2
#define NUM_GRAPHS 16
#define EPSF      1e-5f
#define SCAN_NB   157                 // ceil(40000/256)
#define FIXSC     1048576.0f          // 2^20 fixed-point scale for edge weights

typedef unsigned short u16;
typedef unsigned int   u32;
typedef unsigned long long u64;
using short8 = __attribute__((ext_vector_type(8))) short;
using f32x4  = __attribute__((ext_vector_type(4))) float;

__device__ __forceinline__ float b2f(u16 u) {
    return __uint_as_float(((u32)u) << 16);
}
__device__ __forceinline__ u16 f2b(float f) {
    u32 u = __float_as_uint(f);
    u32 r = (u + 0x7FFFu + ((u >> 16) & 1u)) >> 16;   // RNE
    return (u16)r;
}
__device__ __forceinline__ void gload_lds16(const u16* g, u16* l) {
    __builtin_amdgcn_global_load_lds((const __attribute__((address_space(1))) u32*)g,
                                     (__attribute__((address_space(3))) u32*)l, 16, 0, 0);
}

// ------- pass 1: one u64 atomic per edge: cnt(high24) | fix20(ew) (low40) ---
__global__ __launch_bounds__(256) void pack_kernel(const int* __restrict__ dst,
                                                   const float* __restrict__ ew,
                                                   u64* __restrict__ packed,
                                                   int* __restrict__ eoff) {
    int t = blockIdx.x * blockDim.x + threadIdx.x;
    if (t >= N_EDGES) return;
    int d = dst[t];
    u64 inc = (1ull << 40) | (u64)__float2uint_rn(ew[t] * FIXSC);
    u64 old = atomicAdd(&packed[d], inc);
    eoff[t] = (int)(old >> 40);
}

// ---- scan phase 1 (fused unpack): packed -> dinv, local-excl rowptr, blocksum
__global__ __launch_bounds__(256) void scan_p1_kernel(const u64* __restrict__ packed,
                                                      float* __restrict__ dinv,
                                                      int* __restrict__ rowptr,
                                                      int* __restrict__ blocksum) {
    __shared__ int sd[256];
    const int t = threadIdx.x;
    const int i = blockIdx.x * 256 + t;
    int v = 0;
    if (i < N_NODES) {
        u64 p = packed[i];
        v = (int)(p >> 40);
        float deg = (float)(p & ((1ull << 40) - 1)) * (1.0f / FIXSC);
        dinv[i] = rsqrtf(deg + 1.0f);              // +1 self-loop
    }
    sd[t] = v;
    __syncthreads();
    for (int off = 1; off < 256; off <<= 1) {
        int u = (t >= off) ? sd[t - off] : 0;
        __syncthreads();
        sd[t] += u;
        __syncthreads();
    }
    if (i < N_NODES) rowptr[i] = sd[t] - v;        // local exclusive
    if (t == 255) blocksum[blockIdx.x] = sd[255];
}

__global__ __launch_bounds__(256) void scan_p2_kernel(int* __restrict__ blocksum,
                                                      int* __restrict__ bprefix) {
    __shared__ int sd[256];
    const int t = threadIdx.x;
    const int v = (t < SCAN_NB) ? blocksum[t] : 0;
    sd[t] = v;
    __syncthreads();
    for (int off = 1; off < 256; off <<= 1) {
        int u = (t >= off) ? sd[t - off] : 0;
        __syncthreads();
        sd[t] += u;
        __syncthreads();
    }
    bprefix[t] = sd[t] - v;                        // exclusive block prefix
}

__global__ __launch_bounds__(256) void scan_p3_kernel(int* __restrict__ rowptr,
                                                      const int* __restrict__ bprefix) {
    const int i = blockIdx.x * 256 + threadIdx.x;
    if (i < N_NODES) rowptr[i] += bprefix[blockIdx.x];
    if (i == 0) rowptr[N_NODES] = N_EDGES;
}

// -------- scatter edges into CSR (atomic-free); pair = (src, norm-bits) ----
__global__ __launch_bounds__(256) void scatter_kernel(const int* __restrict__ src,
                                                      const int* __restrict__ dst,
                                                      const float* __restrict__ ew,
                                                      const float* __restrict__ dinv,
                                                      const int* __restrict__ rowptr,
                                                      const int* __restrict__ eoff,
                                                      int2* __restrict__ csr_pair) {
    int t = blockIdx.x * blockDim.x + threadIdx.x;
    if (t >= N_EDGES) return;
    int s = src[t], d = dst[t];
    int pos = rowptr[d] + eoff[t];
    float norm = dinv[s] * ew[t] * dinv[d];
    int2 pr; pr.x = s; pr.y = __float_as_int(norm);
    csr_pair[pos] = pr;
}

// ---------------- casts / transposes ----------------
__global__ __launch_bounds__(256) void cast_x_kernel(const float* __restrict__ x,
                                                     u16* __restrict__ xb) {
    int t = blockIdx.x * blockDim.x + threadIdx.x;
    if (t < N_NODES * IN_CH / 4) {
        float4 v = ((const float4*)x)[t];
        ushort4 o = { f2b(v.x), f2b(v.y), f2b(v.z), f2b(v.w) };
        ((ushort4*)xb)[t] = o;
    }
}

// W[R][C] f32 -> WT[C][R] bf16
__global__ __launch_bounds__(256) void transpose_cast_kernel(const float* __restrict__ W,
                                                             u16* __restrict__ WT,
                                                             int R, int Ccols) {
    int idx = blockIdx.x * blockDim.x + threadIdx.x;
    if (idx >= R * Ccols) return;
    int r = idx / Ccols, c = idx % Ccols;
    WT[(size_t)c * R + r] = f2b(W[idx]);
}

// ---------------- CSR aggregation, bf16 -> bf16 (C=128), 8x unrolled -------
__global__ __launch_bounds__(256) void agg128_kernel(const int* __restrict__ rowptr,
                                                     const int2* __restrict__ csr_pair,
                                                     const float* __restrict__ dinv,
                                                     const u16* __restrict__ xb,
                                                     u16* __restrict__ outb) {
    const int node = (blockIdx.x * blockDim.x + threadIdx.x) >> 6;
    const int lane = threadIdx.x & 63;
    if (node >= N_NODES) return;
    const float ds = dinv[node];
    const float wself = ds * ds;
    const int e0 = rowptr[node], e1 = rowptr[node + 1];
    const int c0 = lane * 2;

    ushort2 v = *(const ushort2*)&xb[(size_t)node * IN_CH + c0];
    float ax = wself * b2f(v.x), ay = wself * b2f(v.y);
    int e = e0;
    for (; e + 8 <= e1; e += 8) {
        int2 pi[8]; ushort2 ui[8];
#pragma unroll
        for (int j = 0; j < 8; ++j) pi[j] = csr_pair[e + j];
#pragma unroll
        for (int j = 0; j < 8; ++j) ui[j] = *(const ushort2*)&xb[(size_t)pi[j].x * IN_CH + c0];
#pragma unroll
        for (int j = 0; j < 8; ++j) {
            float w = __int_as_float(pi[j].y);
            ax += w * b2f(ui[j].x);
            ay += w * b2f(ui[j].y);
        }
    }
    for (; e < e1; ++e) {
        int2 p = csr_pair[e];
        float w = __int_as_float(p.y);
        ushort2 u = *(const ushort2*)&xb[(size_t)p.x * IN_CH + c0];
        ax += w * b2f(u.x);
        ay += w * b2f(u.y);
    }
    ushort2 o = { f2b(ax), f2b(ay) };
    *(ushort2*)&outb[(size_t)node * IN_CH + c0] = o;
}

// ------- CSR aggregation + bias + ReLU + LayerNorm (C=256), 8x unrolled ----
__global__ __launch_bounds__(256) void agg256_ln_kernel(const int* __restrict__ rowptr,
                                                        const int2* __restrict__ csr_pair,
                                                        const float* __restrict__ dinv,
                                                        const u16* __restrict__ hwb,
                                                        const float* __restrict__ bias,
                                                        const float* __restrict__ g,
                                                        const float* __restrict__ be,
                                                        float* __restrict__ out) {
    const int node = (blockIdx.x * blockDim.x + threadIdx.x) >> 6;
    const int lane = threadIdx.x & 63;
    if (node >= N_NODES) return;
    const float ds = dinv[node];
    const float wself = ds * ds;
    const int e0 = rowptr[node], e1 = rowptr[node + 1];
    const int c0 = lane * 4;

    ushort4 v = *(const ushort4*)&hwb[(size_t)node * HID2 + c0];
    float4 acc = { wself * b2f(v.x), wself * b2f(v.y), wself * b2f(v.z), wself * b2f(v.w) };
    int e = e0;
    for (; e + 8 <= e1; e += 8) {
        int2 pi[8]; ushort4 ui[8];
#pragma unroll
        for (int j = 0; j < 8; ++j) pi[j] = csr_pair[e + j];
#pragma unroll
        for (int j = 0; j < 8; ++j) ui[j] = *(const ushort4*)&hwb[(size_t)pi[j].x * HID2 + c0];
#pragma unroll
        for (int j = 0; j < 8; ++j) {
            float w = __int_as_float(pi[j].y);
            acc.x += w * b2f(ui[j].x);
            acc.y += w * b2f(ui[j].y);
            acc.z += w * b2f(ui[j].z);
            acc.w += w * b2f(ui[j].w);
        }
    }
    for (; e < e1; ++e) {
        int2 p = csr_pair[e];
        float w = __int_as_float(p.y);
        ushort4 u = *(const ushort4*)&hwb[(size_t)p.x * HID2 + c0];
        acc.x += w * b2f(u.x);
        acc.y += w * b2f(u.y);
        acc.z += w * b2f(u.z);
        acc.w += w * b2f(u.w);
    }
    // fused bias + ReLU + LayerNorm
    float vv[4];
    float sum = 0.f, sq = 0.f;
#pragma unroll
    for (int j = 0; j < 4; ++j) {
        float xv = ((const float*)&acc)[j] + bias[c0 + j];
        xv = fmaxf(xv, 0.f);
        vv[j] = xv;
        sum += xv;
        sq += xv * xv;
    }
#pragma unroll
    for (int off = 32; off >= 1; off >>= 1) {
        sum += __shfl_xor(sum, off);
        sq  += __shfl_xor(sq, off);
    }
    const float mean = sum * (1.0f / HID2);
    const float var = sq * (1.0f / HID2) - mean * mean;
    const float r = rsqrtf(var + EPSF);
    float4 o;
    o.x = (vv[0] - mean) * r * g[c0 + 0] + be[c0 + 0];
    o.y = (vv[1] - mean) * r * g[c0 + 1] + be[c0 + 1];
    o.z = (vv[2] - mean) * r * g[c0 + 2] + be[c0 + 2];
    o.w = (vv[3] - mean) * r * g[c0 + 3] + be[c0 + 3];
    *(float4*)&out[(size_t)node * HID2 + c0] = o;
}

// ---------------- MFMA GEMM, 128x128 tile, 4 waves, global_load_lds --------
template <int K, int N, int ASTRIDE>
__global__ __launch_bounds__(256) void mfma_gemm128(const u16* __restrict__ A,
                                                    const u16* __restrict__ BT,
                                                    u16* __restrict__ Cb) {
    __shared__ u16 As[128 * 32];
    __shared__ u16 Bs[128 * 32];
    const int t = threadIdx.x;
    const int rowbase = blockIdx.x * 128;
    const int colbase = blockIdx.y * 128;
    const int l = t & 63;
    const int wv = t >> 6;
    const int wm = (wv >> 1) * 64;
    const int wn = (wv & 1) * 64;
    const int fr = l & 15;
    const int fg = l >> 4;

    f32x4 acc[4][4];
#pragma unroll
    for (int a = 0; a < 4; ++a)
#pragma unroll
        for (int b = 0; b < 4; ++b)
            acc[a][b] = (f32x4){0.f, 0.f, 0.f, 0.f};

    const int c0i = wv * 128 + l;
    const int c1i = c0i + 64;
    int ar0 = rowbase + (c0i >> 2); if (ar0 >= N_NODES) ar0 = N_NODES - 1;
    int ar1 = rowbase + (c1i >> 2); if (ar1 >= N_NODES) ar1 = N_NODES - 1;
    const u16* ag0 = A + (size_t)ar0 * ASTRIDE + (c0i & 3) * 8;
    const u16* ag1 = A + (size_t)ar1 * ASTRIDE + (c1i & 3) * 8;
    const u16* bg0 = BT + (size_t)(colbase + (c0i >> 2)) * K + (c0i & 3) * 8;
    const u16* bg1 = BT + (size_t)(colbase + (c1i >> 2)) * K + (c1i & 3) * 8;
    u16* al0 = As + c0i * 8;
    u16* al1 = As + c1i * 8;
    u16* bl0 = Bs + c0i * 8;
    u16* bl1 = Bs + c1i * 8;

    for (int k0 = 0; k0 < K; k0 += 32) {
        gload_lds16(ag0 + k0, al0);
        gload_lds16(ag1 + k0, al1);
        gload_lds16(bg0 + k0, bl0);
        gload_lds16(bg1 + k0, bl1);
        __syncthreads();

        short8 af[4], bf[4];
#pragma unroll
        for (int fm = 0; fm < 4; ++fm)
            af[fm] = *(const short8*)&As[(wm + fm * 16 + fr) * 32 + fg * 8];
#pragma unroll
        for (int fn = 0; fn < 4; ++fn)
            bf[fn] = *(const short8*)&Bs[(wn + fn * 16 + fr) * 32 + fg * 8];
#pragma unroll
        for (int fm = 0; fm < 4; ++fm)
#pragma unroll
            for (int fn = 0; fn < 4; ++fn)
                acc[fm][fn] = __builtin_amdgcn_mfma_f32_16x16x32_bf16(af[fm], bf[fn], acc[fm][fn], 0, 0, 0);
        __syncthreads();
    }

#pragma unroll
    for (int fm = 0; fm < 4; ++fm)
#pragma unroll
        for (int fn = 0; fn < 4; ++fn) {
#pragma unroll
            for (int i = 0; i < 4; ++i) {
                int row = rowbase + wm + fm * 16 + fg * 4 + i;
                if (row < N_NODES) {
                    int col = colbase + wn + fn * 16 + fr;
                    Cb[(size_t)row * N + col] = f2b(acc[fm][fn][i]);
                }
            }
        }
}

// ------- bias + ReLU + LayerNorm, C=512, bf16 in/out, dense, vectorized ----
__global__ __launch_bounds__(256) void relu_ln512b_kernel(u16* __restrict__ io,
                                                          const float* __restrict__ bias,
                                                          const float* __restrict__ g,
                                                          const float* __restrict__ be) {
    const int wv = (blockIdx.x * blockDim.x + threadIdx.x) >> 6;
    const int lane = threadIdx.x & 63;
    if (wv >= N_NODES) return;
    u16* __restrict__ row = io + (size_t)wv * HID1;
    const int c0 = lane * 8;
    short8 raw = *(const short8*)&row[c0];
    float v[8];
    float sum = 0.f, sq = 0.f;
#pragma unroll
    for (int j = 0; j < 8; ++j) {
        float xv = b2f((u16)raw[j]) + bias[c0 + j];
        xv = fmaxf(xv, 0.f);
        v[j] = xv;
        sum += xv;
        sq += xv * xv;
    }
#pragma unroll
    for (int off = 32; off >= 1; off >>= 1) {
        sum += __shfl_xor(sum, off);
        sq  += __shfl_xor(sq, off);
    }
    const float mean = sum * (1.0f / HID1);
    const float var = sq * (1.0f / HID1) - mean * mean;
    const float r = rsqrtf(var + EPSF);
    short8 o;
#pragma unroll
    for (int j = 0; j < 8; ++j)
        o[j] = (short)f2b((v[j] - mean) * r * g[c0 + j] + be[c0 + j]);
    *(short8*)&row[c0] = o;
}

// ---------------- graph boundaries (batch is sorted) ----------------
__global__ __launch_bounds__(64) void bounds_kernel(const int* __restrict__ batch,
                                                    int* __restrict__ gstart) {
    int g = threadIdx.x;
    if (g > NUM_GRAPHS) return;
    int lo = 0, hi = N_NODES;
    while (lo < hi) {
        int mid = (lo + hi) >> 1;
        if (batch[mid] < g) lo = mid + 1; else hi = mid;
    }
    gstart[g] = lo;
}

// ---------------- pool stage: per (graph, chunk) partial sums --------------
__global__ __launch_bounds__(256) void pool2_kernel(const float* __restrict__ h3,
                                                    const int* __restrict__ gstart,
                                                    float* __restrict__ pooled) {
    const int g = blockIdx.x, chunk = blockIdx.y;
    const int s = gstart[g], e = gstart[g + 1];
    const int len = e - s;
    const int c0 = s + (len * chunk) / 16;
    const int c1 = s + (len * (chunk + 1)) / 16;
    float acc = 0.f;
    for (int n = c0; n < c1; ++n)
        acc += h3[(size_t)n * HID2 + threadIdx.x];
    atomicAdd(&pooled[g * HID2 + threadIdx.x], acc);
}

// ---------------- final FC ----------------
__global__ __launch_bounds__(64) void fc_kernel(const float* __restrict__ pooled,
                                                const int* __restrict__ gstart,
                                                const float* __restrict__ Wfc,
                                                const float* __restrict__ bfc,
                                                float* __restrict__ out) {
    const int t = threadIdx.x;
    if (t >= NUM_GRAPHS * OUT_CH) return;
    const int g = t >> 1;
    const int o = t & 1;
    const int len = gstart[g + 1] - gstart[g];
    const float inv = 1.0f / fmaxf((float)len, 1.0f);
    float s = 0.f;
    for (int k = 0; k < HID2; ++k)
        s += pooled[g * HID2 + k] * Wfc[k * OUT_CH + o];
    out[t] = s * inv + bfc[o];
}

extern "C" void kernel_launch(void* const* d_in, const int* in_sizes, int n_in,
                              void* d_out, int out_size, void* d_ws, size_t ws_size,
                              hipStream_t stream) {
    const float* x   = (const float*)d_in[0];
    const int*   ei  = (const int*)d_in[1];
    const float* ew  = (const float*)d_in[2];
    const int*   bat = (const int*)d_in[3];
    const float* W1  = (const float*)d_in[4];
    const float* b1  = (const float*)d_in[5];
    const float* g1  = (const float*)d_in[6];
    const float* be1 = (const float*)d_in[7];
    const float* W2  = (const float*)d_in[8];
    const float* b2  = (const float*)d_in[9];
    const float* g2  = (const float*)d_in[10];
    const float* be2 = (const float*)d_in[11];
    const float* Wfc = (const float*)d_in[12];
    const float* bfc = (const float*)d_in[13];

    const int* srcArr = ei;
    const int* dstArr = ei + N_EDGES;

    float* out = (float*)d_out;
    float* h3  = out;                                   // [40000, 256] f32
    float* fcO = out + (size_t)N_NODES * HID2;

    // workspace layout (f32-element offsets; packed is 8B-aligned at base)
    float* ws       = (float*)d_ws;
    u64*   packed   = (u64*)ws;                         // 40960 u64  (81920 f32)
    float* dinv     = ws + 81920;                       // 40960
    int*   rowptr   = (int*)(ws + 122880);              // 41088 (41001 used)
    int*   gstart   = (int*)(ws + 163968);              // 64
    int*   blocksum = (int*)(ws + 164032);              // 256
    int*   bprefix  = (int*)(ws + 164288);              // 256
    int*   eoff     = (int*)(ws + 164544);              // 640000
    int2*  csr_pair = (int2*)(ws + 804544);             // 640000 int2 (1280000 f32)
    u16*   xb       = (u16*)(ws + 2084544);             // 40000*128 u16
    u16*   agg1b    = (u16*)(ws + 4644544);             // 40000*128 u16
    u16*   hb       = (u16*)(ws + 7204544);             // 40000*512 u16 (dense bf16 h)
    u16*   hwb      = (u16*)(ws + 17444544);            // 40000*256 u16
    u16*   W1T      = (u16*)(ws + 22564544);            // 512*128 u16
    u16*   W2T      = (u16*)(ws + 22597312);            // 256*512 u16
    float* pooled   = ws + 22662848;                    // 16*256

    // 1. degree/count/slot in ONE atomic pass + CSR build (atomic-free scatter)
    hipMemsetAsync(packed, 0, 40960 * sizeof(u64), stream);
    pack_kernel<<<(N_EDGES + 255) / 256, 256, 0, stream>>>(dstArr, ew, packed, eoff);
    scan_p1_kernel<<<SCAN_NB, 256, 0, stream>>>(packed, dinv, rowptr, blocksum);
    scan_p2_kernel<<<1, 256, 0, stream>>>(blocksum, bprefix);
    scan_p3_kernel<<<SCAN_NB, 256, 0, stream>>>(rowptr, bprefix);
    scatter_kernel<<<(N_EDGES + 255) / 256, 256, 0, stream>>>(
        srcArr, dstArr, ew, dinv, rowptr, eoff, csr_pair);

    // 2. param prep
    cast_x_kernel<<<(N_NODES * IN_CH / 4 + 255) / 256, 256, 0, stream>>>(x, xb);
    transpose_cast_kernel<<<(IN_CH * HID1 + 255) / 256, 256, 0, stream>>>(W1, W1T, IN_CH, HID1);
    transpose_cast_kernel<<<(HID1 * HID2 + 255) / 256, 256, 0, stream>>>(W2, W2T, HID1, HID2);

    // 3. layer 1: agg1 = A_norm @ x (bf16), h = agg1 @ W1 (MFMA -> bf16), relu+LN bf16
    agg128_kernel<<<(N_NODES + 3) / 4, 256, 0, stream>>>(
        rowptr, csr_pair, dinv, xb, agg1b);
    {
        dim3 grid((N_NODES + 127) / 128, HID1 / 128);
        mfma_gemm128<IN_CH, HID1, IN_CH><<<grid, 256, 0, stream>>>(agg1b, W1T, hb);
    }
    relu_ln512b_kernel<<<(N_NODES + 3) / 4, 256, 0, stream>>>(hb, b1, g1, be1);

    // 4. layer 2: hw = h @ W2 (MFMA -> bf16), h3 = A_norm @ hw fused relu+LN
    {
        dim3 grid((N_NODES + 127) / 128, HID2 / 128);
        mfma_gemm128<HID1, HID2, HID1><<<grid, 256, 0, stream>>>(hb, W2T, hwb);
    }
    agg256_ln_kernel<<<(N_NODES + 3) / 4, 256, 0, stream>>>(
        rowptr, csr_pair, dinv, hwb, b2, g2, be2, h3);

    // 5. pool + fc
    bounds_kernel<<<1, 64, 0, stream>>>(bat, gstart);
    hipMemsetAsync(pooled, 0, NUM_GRAPHS * HID2 * sizeof(float), stream);
    {
        dim3 grid(NUM_GRAPHS, 16);
        pool2_kernel<<<grid, 256, 0, stream>>>(h3, gstart, pooled);
    }
    fc_kernel<<<1, 64, 0, stream>>>(pooled, gstart, Wfc, bfc, fcO);
}

// Round 10
// 261.523 us; speedup vs baseline: 1.1116x; 1.0098x over previous
//
#include <hip/hip_runtime.h>
#include <hip/hip_bf16.h>

#define N_NODES   40000
#define N_EDGES   640000
#define IN_CH     128
#define HID1      512
#define HID2      256
#define OUT_CH    2
#define NUM_GRAPHS 16
#define EPSF      1e-5f
#define SCAN_NB   157                 // ceil(40000/256)
#define FIXSC     1048576.0f          // 2^20 fixed-point scale for edge weights

typedef unsigned short u16;
typedef unsigned int   u32;
typedef unsigned long long u64;
using short8 = __attribute__((ext_vector_type(8))) short;
using f32x4  = __attribute__((ext_vector_type(4))) float;

__device__ __forceinline__ float b2f(u16 u) {
    return __uint_as_float(((u32)u) << 16);
}
__device__ __forceinline__ u16 f2b(float f) {
    u32 u = __float_as_uint(f);
    u32 r = (u + 0x7FFFu + ((u >> 16) & 1u)) >> 16;   // RNE
    return (u16)r;
}
__device__ __forceinline__ void gload_lds16(const u16* g, u16* l) {
    __builtin_amdgcn_global_load_lds((const __attribute__((address_space(1))) u32*)g,
                                     (__attribute__((address_space(3))) u32*)l, 16, 0, 0);
}

// ------- pass 1: one u64 atomic per edge: cnt(high24) | fix20(ew) (low40) ---
__global__ __launch_bounds__(256) void pack_kernel(const int* __restrict__ dst,
                                                   const float* __restrict__ ew,
                                                   u64* __restrict__ packed,
                                                   int* __restrict__ eoff) {
    int t = blockIdx.x * blockDim.x + threadIdx.x;
    if (t >= N_EDGES) return;
    int d = dst[t];
    u64 inc = (1ull << 40) | (u64)__float2uint_rn(ew[t] * FIXSC);
    u64 old = atomicAdd(&packed[d], inc);
    eoff[t] = (int)(old >> 40);
}

// ---- scan phase 1 (fused unpack): packed -> dinv, local-excl rowptr, blocksum
__global__ __launch_bounds__(256) void scan_p1_kernel(const u64* __restrict__ packed,
                                                      float* __restrict__ dinv,
                                                      int* __restrict__ rowptr,
                                                      int* __restrict__ blocksum) {
    __shared__ int sd[256];
    const int t = threadIdx.x;
    const int i = blockIdx.x * 256 + t;
    int v = 0;
    if (i < N_NODES) {
        u64 p = packed[i];
        v = (int)(p >> 40);
        float deg = (float)(p & ((1ull << 40) - 1)) * (1.0f / FIXSC);
        dinv[i] = rsqrtf(deg + 1.0f);              // +1 self-loop
    }
    sd[t] = v;
    __syncthreads();
    for (int off = 1; off < 256; off <<= 1) {
        int u = (t >= off) ? sd[t - off] : 0;
        __syncthreads();
        sd[t] += u;
        __syncthreads();
    }
    if (i < N_NODES) rowptr[i] = sd[t] - v;        // local exclusive
    if (t == 255) blocksum[blockIdx.x] = sd[255];
}

// ---- scan phase 2 + graph-boundary binary search (both tiny single-block) --
__global__ __launch_bounds__(256) void scan_p2_kernel(int* __restrict__ blocksum,
                                                      int* __restrict__ bprefix,
                                                      const int* __restrict__ batch,
                                                      int* __restrict__ gstart) {
    __shared__ int sd[256];
    const int t = threadIdx.x;
    const int v = (t < SCAN_NB) ? blocksum[t] : 0;
    sd[t] = v;
    __syncthreads();
    for (int off = 1; off < 256; off <<= 1) {
        int u = (t >= off) ? sd[t - off] : 0;
        __syncthreads();
        sd[t] += u;
        __syncthreads();
    }
    bprefix[t] = sd[t] - v;                        // exclusive block prefix
    if (t <= NUM_GRAPHS) {
        int lo = 0, hi = N_NODES;
        while (lo < hi) {
            int mid = (lo + hi) >> 1;
            if (batch[mid] < t) lo = mid + 1; else hi = mid;
        }
        gstart[t] = lo;
    }
}

__global__ __launch_bounds__(256) void scan_p3_kernel(int* __restrict__ rowptr,
                                                      const int* __restrict__ bprefix) {
    const int i = blockIdx.x * 256 + threadIdx.x;
    if (i < N_NODES) rowptr[i] += bprefix[blockIdx.x];
    if (i == 0) rowptr[N_NODES] = N_EDGES;
}

// -------- scatter edges into CSR (atomic-free); pair = (src, norm-bits) ----
__global__ __launch_bounds__(256) void scatter_kernel(const int* __restrict__ src,
                                                      const int* __restrict__ dst,
                                                      const float* __restrict__ ew,
                                                      const float* __restrict__ dinv,
                                                      const int* __restrict__ rowptr,
                                                      const int* __restrict__ eoff,
                                                      int2* __restrict__ csr_pair) {
    int t = blockIdx.x * blockDim.x + threadIdx.x;
    if (t >= N_EDGES) return;
    int s = src[t], d = dst[t];
    int pos = rowptr[d] + eoff[t];
    float norm = dinv[s] * ew[t] * dinv[d];
    int2 pr; pr.x = s; pr.y = __float_as_int(norm);
    csr_pair[pos] = pr;
}

// ---------------- prep: cast x -> bf16; transpose+cast W1, W2 --------------
__global__ __launch_bounds__(256) void prep_kernel(const float* __restrict__ x,
                                                   u16* __restrict__ xb,
                                                   const float* __restrict__ W1,
                                                   u16* __restrict__ W1T,
                                                   const float* __restrict__ W2,
                                                   u16* __restrict__ W2T) {
    int t = blockIdx.x * blockDim.x + threadIdx.x;
    if (t < N_NODES * IN_CH / 4) {
        float4 v = ((const float4*)x)[t];
        ushort4 o = { f2b(v.x), f2b(v.y), f2b(v.z), f2b(v.w) };
        ((ushort4*)xb)[t] = o;
    }
    if (t < IN_CH * HID1) {
        int r = t / HID1, c = t % HID1;
        W1T[(size_t)c * IN_CH + r] = f2b(W1[t]);
    }
    if (t < HID1 * HID2) {
        int r = t / HID2, c = t % HID2;
        W2T[(size_t)c * HID1 + r] = f2b(W2[t]);
    }
}

// ------ CSR aggregation, bf16->bf16 (C=128), 2 edges/wave-iter, 4x staged --
__global__ __launch_bounds__(256) void agg128_kernel(const int* __restrict__ rowptr,
                                                     const int2* __restrict__ csr_pair,
                                                     const float* __restrict__ dinv,
                                                     const u16* __restrict__ xb,
                                                     u16* __restrict__ outb) {
    const int node = (blockIdx.x * blockDim.x + threadIdx.x) >> 6;
    const int l = threadIdx.x & 63;
    if (node >= N_NODES) return;
    const int half = l >> 5, cl = l & 31;
    const float ds = dinv[node];
    const float wself = half ? 0.f : ds * ds;      // self counted once (half 0)
    const int e0 = rowptr[node], e1 = rowptr[node + 1];
    const int c0 = cl * 4;

    ushort4 sv = *(const ushort4*)&xb[(size_t)node * IN_CH + c0];
    float acc[4] = { wself * b2f(sv.x), wself * b2f(sv.y),
                     wself * b2f(sv.z), wself * b2f(sv.w) };
    int e = e0;
    for (; e + 8 <= e1; e += 8) {
        int2 p[4]; ushort4 u[4];
#pragma unroll
        for (int j = 0; j < 4; ++j) p[j] = csr_pair[e + half + 2 * j];
#pragma unroll
        for (int j = 0; j < 4; ++j) u[j] = *(const ushort4*)&xb[(size_t)p[j].x * IN_CH + c0];
#pragma unroll
        for (int j = 0; j < 4; ++j) {
            float w = __int_as_float(p[j].y);
            acc[0] += w * b2f(u[j].x);
            acc[1] += w * b2f(u[j].y);
            acc[2] += w * b2f(u[j].z);
            acc[3] += w * b2f(u[j].w);
        }
    }
    for (int ee = e + half; ee < e1; ee += 2) {
        int2 p = csr_pair[ee];
        float w = __int_as_float(p.y);
        ushort4 u = *(const ushort4*)&xb[(size_t)p.x * IN_CH + c0];
        acc[0] += w * b2f(u.x);
        acc[1] += w * b2f(u.y);
        acc[2] += w * b2f(u.z);
        acc[3] += w * b2f(u.w);
    }
#pragma unroll
    for (int j = 0; j < 4; ++j) acc[j] += __shfl_xor(acc[j], 32);
    float a0 = half ? acc[2] : acc[0];
    float a1 = half ? acc[3] : acc[1];
    ushort2 o = { f2b(a0), f2b(a1) };
    *(ushort2*)&outb[(size_t)node * IN_CH + c0 + half * 2] = o;
}

// -- CSR agg + bias + ReLU + LayerNorm (C=256), 2 edges/wave-iter, 4x staged -
__global__ __launch_bounds__(256) void agg256_ln_kernel(const int* __restrict__ rowptr,
                                                        const int2* __restrict__ csr_pair,
                                                        const float* __restrict__ dinv,
                                                        const u16* __restrict__ hwb,
                                                        const float* __restrict__ bias,
                                                        const float* __restrict__ g,
                                                        const float* __restrict__ be,
                                                        float* __restrict__ out) {
    const int node = (blockIdx.x * blockDim.x + threadIdx.x) >> 6;
    const int l = threadIdx.x & 63;
    if (node >= N_NODES) return;
    const int half = l >> 5, cl = l & 31;
    const float ds = dinv[node];
    const float wself = half ? 0.f : ds * ds;
    const int e0 = rowptr[node], e1 = rowptr[node + 1];
    const int c0 = cl * 8;

    short8 sv = *(const short8*)&hwb[(size_t)node * HID2 + c0];
    float acc[8];
#pragma unroll
    for (int j = 0; j < 8; ++j) acc[j] = wself * b2f((u16)sv[j]);

    int e = e0;
    for (; e + 8 <= e1; e += 8) {
        int2 p[4]; short8 u[4];
#pragma unroll
        for (int j = 0; j < 4; ++j) p[j] = csr_pair[e + half + 2 * j];
#pragma unroll
        for (int j = 0; j < 4; ++j) u[j] = *(const short8*)&hwb[(size_t)p[j].x * HID2 + c0];
#pragma unroll
        for (int j = 0; j < 4; ++j) {
            float w = __int_as_float(p[j].y);
#pragma unroll
            for (int k = 0; k < 8; ++k) acc[k] += w * b2f((u16)u[j][k]);
        }
    }
    for (int ee = e + half; ee < e1; ee += 2) {
        int2 p = csr_pair[ee];
        float w = __int_as_float(p.y);
        short8 u = *(const short8*)&hwb[(size_t)p.x * HID2 + c0];
#pragma unroll
        for (int k = 0; k < 8; ++k) acc[k] += w * b2f((u16)u[k]);
    }
#pragma unroll
    for (int j = 0; j < 8; ++j) acc[j] += __shfl_xor(acc[j], 32);

    // bias + ReLU + stats (full row = 256 ch spread over the 32-lane groups)
    float4 blo = *(const float4*)&bias[c0];
    float4 bhi = *(const float4*)&bias[c0 + 4];
    float vv[8];
    float sum = 0.f, sq = 0.f;
#pragma unroll
    for (int j = 0; j < 8; ++j) {
        float bj = (j < 4) ? ((const float*)&blo)[j] : ((const float*)&bhi)[j - 4];
        float xv = fmaxf(acc[j] + bj, 0.f);
        vv[j] = xv;
        sum += xv;
        sq += xv * xv;
    }
#pragma unroll
    for (int off = 1; off <= 16; off <<= 1) {
        sum += __shfl_xor(sum, off);
        sq  += __shfl_xor(sq, off);
    }
    const float mean = sum * (1.0f / HID2);
    const float var = sq * (1.0f / HID2) - mean * mean;
    const float r = rsqrtf(var + EPSF);

    const int cw = c0 + half * 4;                  // this lane writes 4 channels
    float4 gq = *(const float4*)&g[cw];
    float4 bq = *(const float4*)&be[cw];
    float s0 = half ? vv[4] : vv[0];
    float s1 = half ? vv[5] : vv[1];
    float s2 = half ? vv[6] : vv[2];
    float s3 = half ? vv[7] : vv[3];
    float4 o;
    o.x = (s0 - mean) * r * gq.x + bq.x;
    o.y = (s1 - mean) * r * gq.y + bq.y;
    o.z = (s2 - mean) * r * gq.z + bq.z;
    o.w = (s3 - mean) * r * gq.w + bq.w;
    *(float4*)&out[(size_t)node * HID2 + cw] = o;
}

// ------ fused GEMM1 + bias + ReLU + LayerNorm: 64x512 tile, 8 waves --------
// A: agg1b [40000,128] bf16; BT: W1T [512,128] bf16; H: hb [40000,512] bf16.
__global__ __launch_bounds__(512) void gemm1ln_kernel(const u16* __restrict__ A,
                                                      const u16* __restrict__ BT,
                                                      const float* __restrict__ b1,
                                                      const float* __restrict__ g1,
                                                      const float* __restrict__ be1,
                                                      u16* __restrict__ H) {
    __shared__ u16 As[64 * 32];
    __shared__ u16 Bs[512 * 32];
    __shared__ float lsum[8][64];
    __shared__ float lsq[8][64];
    __shared__ float lmean[64];
    __shared__ float lrstd[64];
    const int t = threadIdx.x;
    const int l = t & 63;
    const int wv = t >> 6;                // 0..7, wave -> 64-col slab
    const int fr = l & 15;
    const int fg = l >> 4;
    const int rowbase = blockIdx.x * 64;  // 625 blocks, exact

    f32x4 acc[4][4];
#pragma unroll
    for (int a = 0; a < 4; ++a)
#pragma unroll
        for (int b = 0; b < 4; ++b)
            acc[a][b] = (f32x4){0.f, 0.f, 0.f, 0.f};

    for (int k0 = 0; k0 < IN_CH; k0 += 32) {
        if (t < 256)                       // As: 64x32 = 256 chunks of 16B
            gload_lds16(A + (size_t)(rowbase + (t >> 2)) * IN_CH + k0 + (t & 3) * 8,
                        As + t * 8);
#pragma unroll
        for (int j = 0; j < 4; ++j) {      // Bs: 512x32 = 2048 chunks
            int c = t + 512 * j;
            gload_lds16(BT + (size_t)(c >> 2) * IN_CH + k0 + (c & 3) * 8,
                        Bs + c * 8);
        }
        __syncthreads();

        short8 af[4], bf[4];
#pragma unroll
        for (int fm = 0; fm < 4; ++fm)
            af[fm] = *(const short8*)&As[(fm * 16 + fr) * 32 + fg * 8];
#pragma unroll
        for (int fn = 0; fn < 4; ++fn)
            bf[fn] = *(const short8*)&Bs[(wv * 64 + fn * 16 + fr) * 32 + fg * 8];
#pragma unroll
        for (int fm = 0; fm < 4; ++fm)
#pragma unroll
            for (int fn = 0; fn < 4; ++fn)
                acc[fm][fn] = __builtin_amdgcn_mfma_f32_16x16x32_bf16(af[fm], bf[fn], acc[fm][fn], 0, 0, 0);
        __syncthreads();
    }

    // epilogue: bias + relu in f32, per-row partial stats
    const int colb = wv * 64;
    float bc[4], gc[4], bec[4];
#pragma unroll
    for (int fn = 0; fn < 4; ++fn) {
        int col = colb + fn * 16 + fr;
        bc[fn] = b1[col];
        gc[fn] = g1[col];
        bec[fn] = be1[col];
    }
    float ps[4][4], pq[4][4];              // [fm][i] per-row partials (4 cols)
#pragma unroll
    for (int fm = 0; fm < 4; ++fm)
#pragma unroll
        for (int i = 0; i < 4; ++i) { ps[fm][i] = 0.f; pq[fm][i] = 0.f; }
#pragma unroll
    for (int fm = 0; fm < 4; ++fm)
#pragma unroll
        for (int fn = 0; fn < 4; ++fn)
#pragma unroll
            for (int i = 0; i < 4; ++i) {
                float xv = fmaxf(acc[fm][fn][i] + bc[fn], 0.f);
                acc[fm][fn][i] = xv;
                ps[fm][i] += xv;
                pq[fm][i] += xv * xv;
            }
    // reduce over fr (16 lanes -> per-row sums over this wave's 64 cols)
#pragma unroll
    for (int off = 1; off < 16; off <<= 1)
#pragma unroll
        for (int fm = 0; fm < 4; ++fm)
#pragma unroll
            for (int i = 0; i < 4; ++i) {
                ps[fm][i] += __shfl_xor(ps[fm][i], off);
                pq[fm][i] += __shfl_xor(pq[fm][i], off);
            }
    if (fr == 0) {
#pragma unroll
        for (int fm = 0; fm < 4; ++fm)
#pragma unroll
            for (int i = 0; i < 4; ++i) {
                int row = fm * 16 + fg * 4 + i;
                lsum[wv][row] = ps[fm][i];
                lsq[wv][row] = pq[fm][i];
            }
    }
    __syncthreads();
    if (t < 64) {
        float s = 0.f, q = 0.f;
#pragma unroll
        for (int w = 0; w < 8; ++w) { s += lsum[w][t]; q += lsq[w][t]; }
        float mean = s * (1.0f / HID1);
        float var = q * (1.0f / HID1) - mean * mean;
        lmean[t] = mean;
        lrstd[t] = rsqrtf(var + EPSF);
    }
    __syncthreads();
#pragma unroll
    for (int fm = 0; fm < 4; ++fm)
#pragma unroll
        for (int fn = 0; fn < 4; ++fn)
#pragma unroll
            for (int i = 0; i < 4; ++i) {
                int row = fm * 16 + fg * 4 + i;
                int col = colb + fn * 16 + fr;
                float o = (acc[fm][fn][i] - lmean[row]) * lrstd[row] * gc[fn] + bec[fn];
                H[(size_t)(rowbase + row) * HID1 + col] = f2b(o);
            }
}

// ---------------- MFMA GEMM, 128x128 tile (gemm2: hb @ W2T -> hwb) ---------
template <int K, int N, int ASTRIDE>
__global__ __launch_bounds__(256) void mfma_gemm128(const u16* __restrict__ A,
                                                    const u16* __restrict__ BT,
                                                    u16* __restrict__ Cb) {
    __shared__ u16 As[128 * 32];
    __shared__ u16 Bs[128 * 32];
    const int t = threadIdx.x;
    const int rowbase = blockIdx.x * 128;
    const int colbase = blockIdx.y * 128;
    const int l = t & 63;
    const int wv = t >> 6;
    const int wm = (wv >> 1) * 64;
    const int wn = (wv & 1) * 64;
    const int fr = l & 15;
    const int fg = l >> 4;

    f32x4 acc[4][4];
#pragma unroll
    for (int a = 0; a < 4; ++a)
#pragma unroll
        for (int b = 0; b < 4; ++b)
            acc[a][b] = (f32x4){0.f, 0.f, 0.f, 0.f};

    const int c0i = wv * 128 + l;
    const int c1i = c0i + 64;
    int ar0 = rowbase + (c0i >> 2); if (ar0 >= N_NODES) ar0 = N_NODES - 1;
    int ar1 = rowbase + (c1i >> 2); if (ar1 >= N_NODES) ar1 = N_NODES - 1;
    const u16* ag0 = A + (size_t)ar0 * ASTRIDE + (c0i & 3) * 8;
    const u16* ag1 = A + (size_t)ar1 * ASTRIDE + (c1i & 3) * 8;
    const u16* bg0 = BT + (size_t)(colbase + (c0i >> 2)) * K + (c0i & 3) * 8;
    const u16* bg1 = BT + (size_t)(colbase + (c1i >> 2)) * K + (c1i & 3) * 8;
    u16* al0 = As + c0i * 8;
    u16* al1 = As + c1i * 8;
    u16* bl0 = Bs + c0i * 8;
    u16* bl1 = Bs + c1i * 8;

    for (int k0 = 0; k0 < K; k0 += 32) {
        gload_lds16(ag0 + k0, al0);
        gload_lds16(ag1 + k0, al1);
        gload_lds16(bg0 + k0, bl0);
        gload_lds16(bg1 + k0, bl1);
        __syncthreads();

        short8 af[4], bf[4];
#pragma unroll
        for (int fm = 0; fm < 4; ++fm)
            af[fm] = *(const short8*)&As[(wm + fm * 16 + fr) * 32 + fg * 8];
#pragma unroll
        for (int fn = 0; fn < 4; ++fn)
            bf[fn] = *(const short8*)&Bs[(wn + fn * 16 + fr) * 32 + fg * 8];
#pragma unroll
        for (int fm = 0; fm < 4; ++fm)
#pragma unroll
            for (int fn = 0; fn < 4; ++fn)
                acc[fm][fn] = __builtin_amdgcn_mfma_f32_16x16x32_bf16(af[fm], bf[fn], acc[fm][fn], 0, 0, 0);
        __syncthreads();
    }

#pragma unroll
    for (int fm = 0; fm < 4; ++fm)
#pragma unroll
        for (int fn = 0; fn < 4; ++fn) {
#pragma unroll
            for (int i = 0; i < 4; ++i) {
                int row = rowbase + wm + fm * 16 + fg * 4 + i;
                if (row < N_NODES) {
                    int col = colbase + wn + fn * 16 + fr;
                    Cb[(size_t)row * N + col] = f2b(acc[fm][fn][i]);
                }
            }
        }
}

// ---------------- pool stage: per (graph, chunk) partials, no atomics ------
__global__ __launch_bounds__(256) void pool2_kernel(const float* __restrict__ h3,
                                                    const int* __restrict__ gstart,
                                                    float* __restrict__ part) {
    const int g = blockIdx.x, chunk = blockIdx.y;
    const int s = gstart[g], e = gstart[g + 1];
    const int len = e - s;
    const int c0 = s + (len * chunk) / 16;
    const int c1 = s + (len * (chunk + 1)) / 16;
    float acc = 0.f;
    for (int n = c0; n < c1; ++n)
        acc += h3[(size_t)n * HID2 + threadIdx.x];
    part[(size_t)(g * 16 + chunk) * HID2 + threadIdx.x] = acc;
}

// ---------------- final FC: reduce partials + dot with Wfc ----------------
__global__ __launch_bounds__(256) void fc_kernel(const float* __restrict__ part,
                                                 const int* __restrict__ gstart,
                                                 const float* __restrict__ Wfc,
                                                 const float* __restrict__ bfc,
                                                 float* __restrict__ out) {
    __shared__ float r0[256], r1[256];
    const int t = threadIdx.x;
    const float w0 = Wfc[t * 2], w1 = Wfc[t * 2 + 1];
    for (int g = 0; g < NUM_GRAPHS; ++g) {
        float v = 0.f;
#pragma unroll
        for (int k = 0; k < 16; ++k)
            v += part[(size_t)(g * 16 + k) * HID2 + t];
        r0[t] = v * w0;
        r1[t] = v * w1;
        __syncthreads();
        for (int off = 128; off >= 1; off >>= 1) {
            if (t < off) { r0[t] += r0[t + off]; r1[t] += r1[t + off]; }
            __syncthreads();
        }
        if (t == 0) {
            float inv = 1.0f / fmaxf((float)(gstart[g + 1] - gstart[g]), 1.0f);
            out[g * 2 + 0] = r0[0] * inv + bfc[0];
            out[g * 2 + 1] = r1[0] * inv + bfc[1];
        }
        __syncthreads();
    }
}

extern "C" void kernel_launch(void* const* d_in, const int* in_sizes, int n_in,
                              void* d_out, int out_size, void* d_ws, size_t ws_size,
                              hipStream_t stream) {
    const float* x   = (const float*)d_in[0];
    const int*   ei  = (const int*)d_in[1];
    const float* ew  = (const float*)d_in[2];
    const int*   bat = (const int*)d_in[3];
    const float* W1  = (const float*)d_in[4];
    const float* b1  = (const float*)d_in[5];
    const float* g1  = (const float*)d_in[6];
    const float* be1 = (const float*)d_in[7];
    const float* W2  = (const float*)d_in[8];
    const float* b2  = (const float*)d_in[9];
    const float* g2  = (const float*)d_in[10];
    const float* be2 = (const float*)d_in[11];
    const float* Wfc = (const float*)d_in[12];
    const float* bfc = (const float*)d_in[13];

    const int* srcArr = ei;
    const int* dstArr = ei + N_EDGES;

    float* out = (float*)d_out;
    float* h3  = out;                                   // [40000, 256] f32
    float* fcO = out + (size_t)N_NODES * HID2;

    // workspace layout (f32-element offsets; NOTE: u16 buffers occupy
    // count/2 f32 slots — 40000*128 u16 = 2,560,000 f32, etc.)
    float* ws       = (float*)d_ws;
    u64*   packed   = (u64*)ws;                         // [0, 81920)
    float* dinv     = ws + 81920;                       // [81920, 122880)
    int*   rowptr   = (int*)(ws + 122880);              // [122880, 163968)
    int*   gstart   = (int*)(ws + 163968);              // [163968, 164032)
    int*   blocksum = (int*)(ws + 164032);              // [164032, 164288)
    int*   bprefix  = (int*)(ws + 164288);              // [164288, 164544)
    int*   eoff     = (int*)(ws + 164544);              // [164544, 804544)
    int2*  csr_pair = (int2*)(ws + 804544);             // [804544, 2084544)
    u16*   xb       = (u16*)(ws + 2084544);             // [2084544, 4644544)  40000*128 u16
    u16*   agg1b    = (u16*)(ws + 4644544);             // [4644544, 7204544)  40000*128 u16
    u16*   hb       = (u16*)(ws + 7204544);             // [7204544, 17444544) 40000*512 u16
    u16*   hwb      = (u16*)(ws + 17444544);            // [17444544, 22564544) 40000*256 u16
    u16*   W1T      = (u16*)(ws + 22564544);            // [22564544, 22597312) 512*128 u16
    u16*   W2T      = (u16*)(ws + 22597312);            // [22597312, 22662848) 256*512 u16
    float* part     = ws + 22662848;                    // [22662848, 22728384) 16*16*256 f32

    // 1. degree/count/slot in ONE atomic pass + CSR build (atomic-free scatter)
    hipMemsetAsync(packed, 0, 40960 * sizeof(u64), stream);
    pack_kernel<<<(N_EDGES + 255) / 256, 256, 0, stream>>>(dstArr, ew, packed, eoff);
    scan_p1_kernel<<<SCAN_NB, 256, 0, stream>>>(packed, dinv, rowptr, blocksum);
    scan_p2_kernel<<<1, 256, 0, stream>>>(blocksum, bprefix, bat, gstart);
    scan_p3_kernel<<<SCAN_NB, 256, 0, stream>>>(rowptr, bprefix);
    scatter_kernel<<<(N_EDGES + 255) / 256, 256, 0, stream>>>(
        srcArr, dstArr, ew, dinv, rowptr, eoff, csr_pair);

    // 2. param prep (one kernel: cast x, transpose W1, W2)
    prep_kernel<<<(N_NODES * IN_CH / 4 + 255) / 256, 256, 0, stream>>>(
        x, xb, W1, W1T, W2, W2T);

    // 3. layer 1: agg1 = A_norm @ x (bf16); fused GEMM1+bias+relu+LN -> hb
    agg128_kernel<<<(N_NODES + 3) / 4, 256, 0, stream>>>(
        rowptr, csr_pair, dinv, xb, agg1b);
    gemm1ln_kernel<<<N_NODES / 64, 512, 0, stream>>>(agg1b, W1T, b1, g1, be1, hb);

    // 4. layer 2: hw = h @ W2 (MFMA -> bf16), h3 = A_norm @ hw fused relu+LN
    {
        dim3 grid((N_NODES + 127) / 128, HID2 / 128);
        mfma_gemm128<HID1, HID2, HID1><<<grid, 256, 0, stream>>>(hb, W2T, hwb);
    }
    agg256_ln_kernel<<<(N_NODES + 3) / 4, 256, 0, stream>>>(
        rowptr, csr_pair, dinv, hwb, b2, g2, be2, h3);

    // 5. pool + fc (partials, no atomics / no memset)
    {
        dim3 grid(NUM_GRAPHS, 16);
        pool2_kernel<<<grid, 256, 0, stream>>>(h3, gstart, part);
    }
    fc_kernel<<<1, 256, 0, stream>>>(part, gstart, Wfc, bfc, fcO);
}

// Round 11
// 258.295 us; speedup vs baseline: 1.1255x; 1.0125x over previous
//
#include <hip/hip_runtime.h>
#include <hip/hip_bf16.h>

#define N_NODES   40000
#define N_EDGES   640000
#define IN_CH     128
#define HID1      512
#define HID2      256
#define OUT_CH    2
#define NUM_GRAPHS 16
#define EPSF      1e-5f
#define SCAN_NB   157                 // ceil(40000/256)
#define FIXSC     1048576.0f          // 2^20 fixed-point scale for edge weights

typedef unsigned short u16;
typedef unsigned int   u32;
typedef unsigned long long u64;
using short8 = __attribute__((ext_vector_type(8))) short;
using f32x4  = __attribute__((ext_vector_type(4))) float;

__device__ __forceinline__ float b2f(u16 u) {
    return __uint_as_float(((u32)u) << 16);
}
__device__ __forceinline__ u16 f2b(float f) {
    u32 u = __float_as_uint(f);
    u32 r = (u + 0x7FFFu + ((u >> 16) & 1u)) >> 16;   // RNE
    return (u16)r;
}
__device__ __forceinline__ void gload_lds16(const u16* g, u16* l) {
    __builtin_amdgcn_global_load_lds((const __attribute__((address_space(1))) u32*)g,
                                     (__attribute__((address_space(3))) u32*)l, 16, 0, 0);
}

// --- fused: per-edge u64 atomic (cnt|fix20(ew)) + x cast + W transposes ----
// pack is atomic-latency-bound; prep is streaming -> co-scheduled in one grid.
__global__ __launch_bounds__(256) void packprep_kernel(const int* __restrict__ dst,
                                                       const float* __restrict__ ew,
                                                       u64* __restrict__ packed,
                                                       int* __restrict__ eoff,
                                                       const float* __restrict__ x,
                                                       u16* __restrict__ xb,
                                                       const float* __restrict__ W1,
                                                       u16* __restrict__ W1T,
                                                       const float* __restrict__ W2,
                                                       u16* __restrict__ W2T) {
    int t = blockIdx.x * blockDim.x + threadIdx.x;
    if (t < N_EDGES) {
        int d = dst[t];
        u64 inc = (1ull << 40) | (u64)__float2uint_rn(ew[t] * FIXSC);
        u64 old = atomicAdd(&packed[d], inc);
        eoff[t] = (int)(old >> 40);
    }
    if (t < N_NODES * IN_CH / 4) {
        float4 v = ((const float4*)x)[t];
        ushort4 o = { f2b(v.x), f2b(v.y), f2b(v.z), f2b(v.w) };
        ((ushort4*)xb)[t] = o;
    }
    if (t < IN_CH * HID1) {
        int r = t / HID1, c = t % HID1;
        W1T[(size_t)c * IN_CH + r] = f2b(W1[t]);
    }
    if (t < HID1 * HID2) {
        int r = t / HID2, c = t % HID2;
        W2T[(size_t)c * HID1 + r] = f2b(W2[t]);
    }
}

// ---- scan phase 1 (fused unpack): packed -> dinv, local-excl rowptr, blocksum
__global__ __launch_bounds__(256) void scan_p1_kernel(const u64* __restrict__ packed,
                                                      float* __restrict__ dinv,
                                                      int* __restrict__ rowptr,
                                                      int* __restrict__ blocksum) {
    __shared__ int sd[256];
    const int t = threadIdx.x;
    const int i = blockIdx.x * 256 + t;
    int v = 0;
    if (i < N_NODES) {
        u64 p = packed[i];
        v = (int)(p >> 40);
        float deg = (float)(p & ((1ull << 40) - 1)) * (1.0f / FIXSC);
        dinv[i] = rsqrtf(deg + 1.0f);              // +1 self-loop
    }
    sd[t] = v;
    __syncthreads();
    for (int off = 1; off < 256; off <<= 1) {
        int u = (t >= off) ? sd[t - off] : 0;
        __syncthreads();
        sd[t] += u;
        __syncthreads();
    }
    if (i < N_NODES) rowptr[i] = sd[t] - v;        // local exclusive
    if (t == 255) blocksum[blockIdx.x] = sd[255];
}

// ---- scan phase 2 + graph-boundary binary search (both tiny single-block) --
__global__ __launch_bounds__(256) void scan_p2_kernel(int* __restrict__ blocksum,
                                                      int* __restrict__ bprefix,
                                                      const int* __restrict__ batch,
                                                      int* __restrict__ gstart) {
    __shared__ int sd[256];
    const int t = threadIdx.x;
    const int v = (t < SCAN_NB) ? blocksum[t] : 0;
    sd[t] = v;
    __syncthreads();
    for (int off = 1; off < 256; off <<= 1) {
        int u = (t >= off) ? sd[t - off] : 0;
        __syncthreads();
        sd[t] += u;
        __syncthreads();
    }
    bprefix[t] = sd[t] - v;                        // exclusive block prefix
    if (t <= NUM_GRAPHS) {
        int lo = 0, hi = N_NODES;
        while (lo < hi) {
            int mid = (lo + hi) >> 1;
            if (batch[mid] < t) lo = mid + 1; else hi = mid;
        }
        gstart[t] = lo;
    }
}

__global__ __launch_bounds__(256) void scan_p3_kernel(int* __restrict__ rowptr,
                                                      const int* __restrict__ bprefix) {
    const int i = blockIdx.x * 256 + threadIdx.x;
    if (i < N_NODES) rowptr[i] += bprefix[blockIdx.x];
    if (i == 0) rowptr[N_NODES] = N_EDGES;
}

// -------- scatter edges into CSR (atomic-free); pair = (src, norm-bits) ----
__global__ __launch_bounds__(256) void scatter_kernel(const int* __restrict__ src,
                                                      const int* __restrict__ dst,
                                                      const float* __restrict__ ew,
                                                      const float* __restrict__ dinv,
                                                      const int* __restrict__ rowptr,
                                                      const int* __restrict__ eoff,
                                                      int2* __restrict__ csr_pair) {
    int t = blockIdx.x * blockDim.x + threadIdx.x;
    if (t >= N_EDGES) return;
    int s = src[t], d = dst[t];
    int pos = rowptr[d] + eoff[t];
    float norm = dinv[s] * ew[t] * dinv[d];
    int2 pr; pr.x = s; pr.y = __float_as_int(norm);
    csr_pair[pos] = pr;
}

// ------ CSR aggregation, bf16->bf16 (C=128), 2 edges/wave-iter, 4x staged --
__global__ __launch_bounds__(256) void agg128_kernel(const int* __restrict__ rowptr,
                                                     const int2* __restrict__ csr_pair,
                                                     const float* __restrict__ dinv,
                                                     const u16* __restrict__ xb,
                                                     u16* __restrict__ outb) {
    const int node = (blockIdx.x * blockDim.x + threadIdx.x) >> 6;
    const int l = threadIdx.x & 63;
    if (node >= N_NODES) return;
    const int half = l >> 5, cl = l & 31;
    const float ds = dinv[node];
    const float wself = half ? 0.f : ds * ds;      // self counted once (half 0)
    const int e0 = rowptr[node], e1 = rowptr[node + 1];
    const int c0 = cl * 4;

    ushort4 sv = *(const ushort4*)&xb[(size_t)node * IN_CH + c0];
    float acc[4] = { wself * b2f(sv.x), wself * b2f(sv.y),
                     wself * b2f(sv.z), wself * b2f(sv.w) };
    int e = e0;
    for (; e + 8 <= e1; e += 8) {
        int2 p[4]; ushort4 u[4];
#pragma unroll
        for (int j = 0; j < 4; ++j) p[j] = csr_pair[e + half + 2 * j];
#pragma unroll
        for (int j = 0; j < 4; ++j) u[j] = *(const ushort4*)&xb[(size_t)p[j].x * IN_CH + c0];
#pragma unroll
        for (int j = 0; j < 4; ++j) {
            float w = __int_as_float(p[j].y);
            acc[0] += w * b2f(u[j].x);
            acc[1] += w * b2f(u[j].y);
            acc[2] += w * b2f(u[j].z);
            acc[3] += w * b2f(u[j].w);
        }
    }
    for (int ee = e + half; ee < e1; ee += 2) {
        int2 p = csr_pair[ee];
        float w = __int_as_float(p.y);
        ushort4 u = *(const ushort4*)&xb[(size_t)p.x * IN_CH + c0];
        acc[0] += w * b2f(u.x);
        acc[1] += w * b2f(u.y);
        acc[2] += w * b2f(u.z);
        acc[3] += w * b2f(u.w);
    }
#pragma unroll
    for (int j = 0; j < 4; ++j) acc[j] += __shfl_xor(acc[j], 32);
    float a0 = half ? acc[2] : acc[0];
    float a1 = half ? acc[3] : acc[1];
    ushort2 o = { f2b(a0), f2b(a1) };
    *(ushort2*)&outb[(size_t)node * IN_CH + c0 + half * 2] = o;
}

// -- CSR agg + bias + ReLU + LayerNorm (C=256), 2 edges/wave-iter, 4x staged -
__global__ __launch_bounds__(256) void agg256_ln_kernel(const int* __restrict__ rowptr,
                                                        const int2* __restrict__ csr_pair,
                                                        const float* __restrict__ dinv,
                                                        const u16* __restrict__ hwb,
                                                        const float* __restrict__ bias,
                                                        const float* __restrict__ g,
                                                        const float* __restrict__ be,
                                                        float* __restrict__ out) {
    const int node = (blockIdx.x * blockDim.x + threadIdx.x) >> 6;
    const int l = threadIdx.x & 63;
    if (node >= N_NODES) return;
    const int half = l >> 5, cl = l & 31;
    const float ds = dinv[node];
    const float wself = half ? 0.f : ds * ds;
    const int e0 = rowptr[node], e1 = rowptr[node + 1];
    const int c0 = cl * 8;

    short8 sv = *(const short8*)&hwb[(size_t)node * HID2 + c0];
    float acc[8];
#pragma unroll
    for (int j = 0; j < 8; ++j) acc[j] = wself * b2f((u16)sv[j]);

    int e = e0;
    for (; e + 8 <= e1; e += 8) {
        int2 p[4]; short8 u[4];
#pragma unroll
        for (int j = 0; j < 4; ++j) p[j] = csr_pair[e + half + 2 * j];
#pragma unroll
        for (int j = 0; j < 4; ++j) u[j] = *(const short8*)&hwb[(size_t)p[j].x * HID2 + c0];
#pragma unroll
        for (int j = 0; j < 4; ++j) {
            float w = __int_as_float(p[j].y);
#pragma unroll
            for (int k = 0; k < 8; ++k) acc[k] += w * b2f((u16)u[j][k]);
        }
    }
    for (int ee = e + half; ee < e1; ee += 2) {
        int2 p = csr_pair[ee];
        float w = __int_as_float(p.y);
        short8 u = *(const short8*)&hwb[(size_t)p.x * HID2 + c0];
#pragma unroll
        for (int k = 0; k < 8; ++k) acc[k] += w * b2f((u16)u[k]);
    }
#pragma unroll
    for (int j = 0; j < 8; ++j) acc[j] += __shfl_xor(acc[j], 32);

    // bias + ReLU + stats (full row = 256 ch spread over the 32-lane groups)
    float4 blo = *(const float4*)&bias[c0];
    float4 bhi = *(const float4*)&bias[c0 + 4];
    float vv[8];
    float sum = 0.f, sq = 0.f;
#pragma unroll
    for (int j = 0; j < 8; ++j) {
        float bj = (j < 4) ? ((const float*)&blo)[j] : ((const float*)&bhi)[j - 4];
        float xv = fmaxf(acc[j] + bj, 0.f);
        vv[j] = xv;
        sum += xv;
        sq += xv * xv;
    }
#pragma unroll
    for (int off = 1; off <= 16; off <<= 1) {
        sum += __shfl_xor(sum, off);
        sq  += __shfl_xor(sq, off);
    }
    const float mean = sum * (1.0f / HID2);
    const float var = sq * (1.0f / HID2) - mean * mean;
    const float r = rsqrtf(var + EPSF);

    const int cw = c0 + half * 4;                  // this lane writes 4 channels
    float4 gq = *(const float4*)&g[cw];
    float4 bq = *(const float4*)&be[cw];
    float s0 = half ? vv[4] : vv[0];
    float s1 = half ? vv[5] : vv[1];
    float s2 = half ? vv[6] : vv[2];
    float s3 = half ? vv[7] : vv[3];
    float4 o;
    o.x = (s0 - mean) * r * gq.x + bq.x;
    o.y = (s1 - mean) * r * gq.y + bq.y;
    o.z = (s2 - mean) * r * gq.z + bq.z;
    o.w = (s3 - mean) * r * gq.w + bq.w;
    *(float4*)&out[(size_t)node * HID2 + cw] = o;
}

// ------ fused GEMM1 + bias + ReLU + LayerNorm: 64x512 tile, 8 waves --------
// A: agg1b [40000,128] bf16; BT: W1T [512,128] bf16; H: hb [40000,512] bf16.
__global__ __launch_bounds__(512) void gemm1ln_kernel(const u16* __restrict__ A,
                                                      const u16* __restrict__ BT,
                                                      const float* __restrict__ b1,
                                                      const float* __restrict__ g1,
                                                      const float* __restrict__ be1,
                                                      u16* __restrict__ H) {
    __shared__ u16 As[64 * 32];
    __shared__ u16 Bs[512 * 32];
    __shared__ float lsum[8][64];
    __shared__ float lsq[8][64];
    __shared__ float lmean[64];
    __shared__ float lrstd[64];
    const int t = threadIdx.x;
    const int l = t & 63;
    const int wv = t >> 6;                // 0..7, wave -> 64-col slab
    const int fr = l & 15;
    const int fg = l >> 4;
    const int rowbase = blockIdx.x * 64;  // 625 blocks, exact

    f32x4 acc[4][4];
#pragma unroll
    for (int a = 0; a < 4; ++a)
#pragma unroll
        for (int b = 0; b < 4; ++b)
            acc[a][b] = (f32x4){0.f, 0.f, 0.f, 0.f};

    for (int k0 = 0; k0 < IN_CH; k0 += 32) {
        if (t < 256)                       // As: 64x32 = 256 chunks of 16B
            gload_lds16(A + (size_t)(rowbase + (t >> 2)) * IN_CH + k0 + (t & 3) * 8,
                        As + t * 8);
#pragma unroll
        for (int j = 0; j < 4; ++j) {      // Bs: 512x32 = 2048 chunks
            int c = t + 512 * j;
            gload_lds16(BT + (size_t)(c >> 2) * IN_CH + k0 + (c & 3) * 8,
                        Bs + c * 8);
        }
        __syncthreads();

        short8 af[4], bf[4];
#pragma unroll
        for (int fm = 0; fm < 4; ++fm)
            af[fm] = *(const short8*)&As[(fm * 16 + fr) * 32 + fg * 8];
#pragma unroll
        for (int fn = 0; fn < 4; ++fn)
            bf[fn] = *(const short8*)&Bs[(wv * 64 + fn * 16 + fr) * 32 + fg * 8];
#pragma unroll
        for (int fm = 0; fm < 4; ++fm)
#pragma unroll
            for (int fn = 0; fn < 4; ++fn)
                acc[fm][fn] = __builtin_amdgcn_mfma_f32_16x16x32_bf16(af[fm], bf[fn], acc[fm][fn], 0, 0, 0);
        __syncthreads();
    }

    // epilogue: bias + relu in f32, per-row partial stats
    const int colb = wv * 64;
    float bc[4], gc[4], bec[4];
#pragma unroll
    for (int fn = 0; fn < 4; ++fn) {
        int col = colb + fn * 16 + fr;
        bc[fn] = b1[col];
        gc[fn] = g1[col];
        bec[fn] = be1[col];
    }
    float ps[4][4], pq[4][4];              // [fm][i] per-row partials (4 cols)
#pragma unroll
    for (int fm = 0; fm < 4; ++fm)
#pragma unroll
        for (int i = 0; i < 4; ++i) { ps[fm][i] = 0.f; pq[fm][i] = 0.f; }
#pragma unroll
    for (int fm = 0; fm < 4; ++fm)
#pragma unroll
        for (int fn = 0; fn < 4; ++fn)
#pragma unroll
            for (int i = 0; i < 4; ++i) {
                float xv = fmaxf(acc[fm][fn][i] + bc[fn], 0.f);
                acc[fm][fn][i] = xv;
                ps[fm][i] += xv;
                pq[fm][i] += xv * xv;
            }
    // reduce over fr (16 lanes -> per-row sums over this wave's 64 cols)
#pragma unroll
    for (int off = 1; off < 16; off <<= 1)
#pragma unroll
        for (int fm = 0; fm < 4; ++fm)
#pragma unroll
            for (int i = 0; i < 4; ++i) {
                ps[fm][i] += __shfl_xor(ps[fm][i], off);
                pq[fm][i] += __shfl_xor(pq[fm][i], off);
            }
    if (fr == 0) {
#pragma unroll
        for (int fm = 0; fm < 4; ++fm)
#pragma unroll
            for (int i = 0; i < 4; ++i) {
                int row = fm * 16 + fg * 4 + i;
                lsum[wv][row] = ps[fm][i];
                lsq[wv][row] = pq[fm][i];
            }
    }
    __syncthreads();
    if (t < 64) {
        float s = 0.f, q = 0.f;
#pragma unroll
        for (int w = 0; w < 8; ++w) { s += lsum[w][t]; q += lsq[w][t]; }
        float mean = s * (1.0f / HID1);
        float var = q * (1.0f / HID1) - mean * mean;
        lmean[t] = mean;
        lrstd[t] = rsqrtf(var + EPSF);
    }
    __syncthreads();
#pragma unroll
    for (int fm = 0; fm < 4; ++fm)
#pragma unroll
        for (int fn = 0; fn < 4; ++fn)
#pragma unroll
            for (int i = 0; i < 4; ++i) {
                int row = fm * 16 + fg * 4 + i;
                int col = colb + fn * 16 + fr;
                float o = (acc[fm][fn][i] - lmean[row]) * lrstd[row] * gc[fn] + bec[fn];
                H[(size_t)(rowbase + row) * HID1 + col] = f2b(o);
            }
}

// ------- GEMM2, full-N tile: 128 rows x 256 cols, 8 waves, 512 threads -----
// A: hb [40000,512] bf16; BT: W2T [256,512] bf16; Cb: hwb [40000,256] bf16.
// A is read ONCE (single col-tile) vs twice in the 128x128 version.
__global__ __launch_bounds__(512) void gemm2_kernel(const u16* __restrict__ A,
                                                    const u16* __restrict__ BT,
                                                    u16* __restrict__ Cb) {
    __shared__ u16 As[128 * 32];
    __shared__ u16 Bs[256 * 32];
    const int t = threadIdx.x;
    const int l = t & 63;
    const int wv = t >> 6;                 // 8 waves: 2 row-halves x 4 col-quads
    const int wm = (wv >> 2) * 64;
    const int wn = (wv & 3) * 64;
    const int fr = l & 15;
    const int fg = l >> 4;
    const int rowbase = blockIdx.x * 128;  // 313 blocks (tail guarded)

    f32x4 acc[4][4];
#pragma unroll
    for (int a = 0; a < 4; ++a)
#pragma unroll
        for (int b = 0; b < 4; ++b)
            acc[a][b] = (f32x4){0.f, 0.f, 0.f, 0.f};

    // staging addresses (per k-step offsets added in loop)
    int ar = rowbase + (t >> 2); if (ar >= N_NODES) ar = N_NODES - 1;
    const u16* ag = A + (size_t)ar * HID1 + (t & 3) * 8;       // As chunk t
    const int cb0 = t, cb1 = t + 512;                           // Bs chunks
    const u16* bg0 = BT + (size_t)(cb0 >> 2) * HID1 + (cb0 & 3) * 8;
    const u16* bg1 = BT + (size_t)(cb1 >> 2) * HID1 + (cb1 & 3) * 8;

    for (int k0 = 0; k0 < HID1; k0 += 32) {
        gload_lds16(ag + k0, As + t * 8);
        gload_lds16(bg0 + k0, Bs + cb0 * 8);
        gload_lds16(bg1 + k0, Bs + cb1 * 8);
        __syncthreads();

        short8 af[4], bf[4];
#pragma unroll
        for (int fm = 0; fm < 4; ++fm)
            af[fm] = *(const short8*)&As[(wm + fm * 16 + fr) * 32 + fg * 8];
#pragma unroll
        for (int fn = 0; fn < 4; ++fn)
            bf[fn] = *(const short8*)&Bs[(wn + fn * 16 + fr) * 32 + fg * 8];
#pragma unroll
        for (int fm = 0; fm < 4; ++fm)
#pragma unroll
            for (int fn = 0; fn < 4; ++fn)
                acc[fm][fn] = __builtin_amdgcn_mfma_f32_16x16x32_bf16(af[fm], bf[fn], acc[fm][fn], 0, 0, 0);
        __syncthreads();
    }

#pragma unroll
    for (int fm = 0; fm < 4; ++fm)
#pragma unroll
        for (int fn = 0; fn < 4; ++fn) {
#pragma unroll
            for (int i = 0; i < 4; ++i) {
                int row = rowbase + wm + fm * 16 + fg * 4 + i;
                if (row < N_NODES) {
                    int col = wn + fn * 16 + fr;
                    Cb[(size_t)row * HID2 + col] = f2b(acc[fm][fn][i]);
                }
            }
        }
}

// ---------------- pool stage: per (graph, chunk) partials, no atomics ------
__global__ __launch_bounds__(256) void pool2_kernel(const float* __restrict__ h3,
                                                    const int* __restrict__ gstart,
                                                    float* __restrict__ part) {
    const int g = blockIdx.x, chunk = blockIdx.y;
    const int s = gstart[g], e = gstart[g + 1];
    const int len = e - s;
    const int c0 = s + (len * chunk) / 16;
    const int c1 = s + (len * (chunk + 1)) / 16;
    float acc = 0.f;
    for (int n = c0; n < c1; ++n)
        acc += h3[(size_t)n * HID2 + threadIdx.x];
    part[(size_t)(g * 16 + chunk) * HID2 + threadIdx.x] = acc;
}

// ---------------- final FC: reduce partials + dot with Wfc ----------------
__global__ __launch_bounds__(256) void fc_kernel(const float* __restrict__ part,
                                                 const int* __restrict__ gstart,
                                                 const float* __restrict__ Wfc,
                                                 const float* __restrict__ bfc,
                                                 float* __restrict__ out) {
    __shared__ float r0[256], r1[256];
    const int t = threadIdx.x;
    const float w0 = Wfc[t * 2], w1 = Wfc[t * 2 + 1];
    for (int g = 0; g < NUM_GRAPHS; ++g) {
        float v = 0.f;
#pragma unroll
        for (int k = 0; k < 16; ++k)
            v += part[(size_t)(g * 16 + k) * HID2 + t];
        r0[t] = v * w0;
        r1[t] = v * w1;
        __syncthreads();
        for (int off = 128; off >= 1; off >>= 1) {
            if (t < off) { r0[t] += r0[t + off]; r1[t] += r1[t + off]; }
            __syncthreads();
        }
        if (t == 0) {
            float inv = 1.0f / fmaxf((float)(gstart[g + 1] - gstart[g]), 1.0f);
            out[g * 2 + 0] = r0[0] * inv + bfc[0];
            out[g * 2 + 1] = r1[0] * inv + bfc[1];
        }
        __syncthreads();
    }
}

extern "C" void kernel_launch(void* const* d_in, const int* in_sizes, int n_in,
                              void* d_out, int out_size, void* d_ws, size_t ws_size,
                              hipStream_t stream) {
    const float* x   = (const float*)d_in[0];
    const int*   ei  = (const int*)d_in[1];
    const float* ew  = (const float*)d_in[2];
    const int*   bat = (const int*)d_in[3];
    const float* W1  = (const float*)d_in[4];
    const float* b1  = (const float*)d_in[5];
    const float* g1  = (const float*)d_in[6];
    const float* be1 = (const float*)d_in[7];
    const float* W2  = (const float*)d_in[8];
    const float* b2  = (const float*)d_in[9];
    const float* g2  = (const float*)d_in[10];
    const float* be2 = (const float*)d_in[11];
    const float* Wfc = (const float*)d_in[12];
    const float* bfc = (const float*)d_in[13];

    const int* srcArr = ei;
    const int* dstArr = ei + N_EDGES;

    float* out = (float*)d_out;
    float* h3  = out;                                   // [40000, 256] f32
    float* fcO = out + (size_t)N_NODES * HID2;

    // workspace layout (f32-element offsets; u16 buffers = count/2 f32 slots)
    float* ws       = (float*)d_ws;
    u64*   packed   = (u64*)ws;                         // [0, 81920)
    float* dinv     = ws + 81920;                       // [81920, 122880)
    int*   rowptr   = (int*)(ws + 122880);              // [122880, 163968)
    int*   gstart   = (int*)(ws + 163968);              // [163968, 164032)
    int*   blocksum = (int*)(ws + 164032);              // [164032, 164288)
    int*   bprefix  = (int*)(ws + 164288);              // [164288, 164544)
    int*   eoff     = (int*)(ws + 164544);              // [164544, 804544)
    int2*  csr_pair = (int2*)(ws + 804544);             // [804544, 2084544)
    u16*   xb       = (u16*)(ws + 2084544);             // [2084544, 4644544)  40000*128 u16
    u16*   agg1b    = (u16*)(ws + 4644544);             // [4644544, 7204544)  40000*128 u16
    u16*   hb       = (u16*)(ws + 7204544);             // [7204544, 17444544) 40000*512 u16
    u16*   hwb      = (u16*)(ws + 17444544);            // [17444544, 22564544) 40000*256 u16
    u16*   W1T      = (u16*)(ws + 22564544);            // [22564544, 22597312) 512*128 u16
    u16*   W2T      = (u16*)(ws + 22597312);            // [22597312, 22662848) 256*512 u16
    float* part     = ws + 22662848;                    // [22662848, 22728384) 16*16*256 f32

    // 1. fused pack (per-edge atomic) + prep (casts/transposes)
    hipMemsetAsync(packed, 0, 40960 * sizeof(u64), stream);
    packprep_kernel<<<(N_NODES * IN_CH / 4 + 255) / 256, 256, 0, stream>>>(
        dstArr, ew, packed, eoff, x, xb, W1, W1T, W2, W2T);

    // 2. CSR build (scan + atomic-free scatter)
    scan_p1_kernel<<<SCAN_NB, 256, 0, stream>>>(packed, dinv, rowptr, blocksum);
    scan_p2_kernel<<<1, 256, 0, stream>>>(blocksum, bprefix, bat, gstart);
    scan_p3_kernel<<<SCAN_NB, 256, 0, stream>>>(rowptr, bprefix);
    scatter_kernel<<<(N_EDGES + 255) / 256, 256, 0, stream>>>(
        srcArr, dstArr, ew, dinv, rowptr, eoff, csr_pair);

    // 3. layer 1: agg1 = A_norm @ x (bf16); fused GEMM1+bias+relu+LN -> hb
    agg128_kernel<<<(N_NODES + 3) / 4, 256, 0, stream>>>(
        rowptr, csr_pair, dinv, xb, agg1b);
    gemm1ln_kernel<<<N_NODES / 64, 512, 0, stream>>>(agg1b, W1T, b1, g1, be1, hb);

    // 4. layer 2: hw = h @ W2 (full-N MFMA tile), h3 = A_norm @ hw + relu+LN
    gemm2_kernel<<<(N_NODES + 127) / 128, 512, 0, stream>>>(hb, W2T, hwb);
    agg256_ln_kernel<<<(N_NODES + 3) / 4, 256, 0, stream>>>(
        rowptr, csr_pair, dinv, hwb, b2, g2, be2, h3);

    // 5. pool + fc (partials, no atomics / no memset)
    {
        dim3 grid(NUM_GRAPHS, 16);
        pool2_kernel<<<grid, 256, 0, stream>>>(h3, gstart, part);
    }
    fc_kernel<<<1, 256, 0, stream>>>(part, gstart, Wfc, bfc, fcO);
}